// Round 14
// baseline (756.162 us; speedup 1.0000x reference)
//
#include <hip/hip_runtime.h>
#include <math.h>

#define D_MODEL  2048
#define D_INNER  2048
#define N_QK     32
#define N_V      32
#define D_STATE  64
#define D_CONV   4
#define CHUNK    128
#define CONV_DIM 6144      // D_INNER + 2*N_QK*D_STATE
#define IN_OUT   8224      // 2*D_INNER + 2*N_QK*D_STATE + N_V
#define BATCH    2
#define SEQ      4096
#define M_ROWS   (BATCH*SEQ)   // 8192
#define NCHUNK   (SEQ/CHUNK)   // 32

typedef unsigned short bf16_t;
typedef __attribute__((ext_vector_type(4))) float f32x4;
typedef __attribute__((ext_vector_type(8))) short bf16x8;

// swizzled row-major LDS index (elem units); XOR bits 3-5 spread rows over banks
#define SWZ64(r,c)  ((((r)*64)  + (c)) ^ (((r)&7)<<3))
#define SWZ128(r,c) ((((r)*128) + (c)) ^ (((r)&7)<<3))

__device__ __forceinline__ float b2f(bf16_t u) {
    union { unsigned int i; float f; } w; w.i = ((unsigned int)u) << 16; return w.f;
}
__device__ __forceinline__ bf16_t f2b(float f) {
    unsigned int x = __float_as_uint(f);
    return (bf16_t)((x + 0x7FFFu + ((x >> 16) & 1u)) >> 16);   // RNE
}
__device__ __forceinline__ void store4b(bf16_t* dst, float4 v) {
    ushort4 u; u.x = f2b(v.x); u.y = f2b(v.y); u.z = f2b(v.z); u.w = f2b(v.w);
    *reinterpret_cast<ushort4*>(dst) = u;
}

__device__ __forceinline__ void gload_lds16(const bf16_t* g, bf16_t* l) {
    __builtin_amdgcn_global_load_lds((const __attribute__((address_space(1))) void*)g,
                                     (__attribute__((address_space(3))) void*)l,
                                     16, 0, 0);
}

// ---------------------------------------------------------------------------
// fused fp32 -> bf16 convert for 3 segments (u, W_in, W_out) in one dispatch
// ---------------------------------------------------------------------------
__global__ __launch_bounds__(256) void f2b3_kernel(const float* __restrict__ a0, bf16_t* __restrict__ o0, long n0,
                                                   const float* __restrict__ a1, bf16_t* __restrict__ o1, long n1,
                                                   const float* __restrict__ a2, bf16_t* __restrict__ o2, long n2)
{
    long i = ((long)blockIdx.x * 256 + threadIdx.x) * 4;
    const float* in; bf16_t* out;
    if (i < n0)            { in = a0 + i; out = o0 + i; }
    else if (i < n0 + n1)  { i -= n0; in = a1 + i; out = o1 + i; }
    else if (i < n0 + n1 + n2) { i -= n0 + n1; in = a2 + i; out = o2 + i; }
    else return;
    float4 v = *reinterpret_cast<const float4*>(in);
    ushort4 o;
    o.x = f2b(v.x); o.y = f2b(v.y); o.z = f2b(v.z); o.w = f2b(v.w);
    *reinterpret_cast<ushort4*>(out) = o;
}

// ---------------------------------------------------------------------------
// 256x256 bf16 MFMA NT-GEMM, K-half counted-vmcnt pipeline, 2 barriers/tile.
// TAIL: grid has 64 extra wgs (wg >= 32*NTB) computing the 32-col A_log tail
// (B rows NTB*256.., C cols NTB*256..) as 128x32 tiles, concurrent with main.
// ---------------------------------------------------------------------------
template<int NTB, int K, bool OBF16, bool TAIL>
__global__ __launch_bounds__(512, 2) void gemm256(const bf16_t* __restrict__ A,
                                                  const bf16_t* __restrict__ B,
                                                  void* __restrict__ Cv,
                                                  long ldc)
{
    constexpr int BK = 64;
    constexpr int NT = K / BK;
    __shared__ bf16_t As[2][2][8192];   // [buf][kh][1024 slots * 8 elems]
    __shared__ bf16_t Bs[2][2][8192];

    const int nwg = gridDim.x;
    const int bid = blockIdx.x;
    const int wg  = ((nwg & 7) == 0) ? ((bid & 7) * (nwg >> 3) + (bid >> 3)) : bid;

    const int tid  = threadIdx.x;
    const int lane = tid & 63;
    const int wv   = tid >> 6;
    const int l15  = lane & 15, l4 = lane >> 4;

    if (TAIL && wg >= 32 * NTB) {
        // ---- tail path: 128 x 32 tile, simple single-buffer loop ----
        const int bmT = (wg - 32 * NTB) * 128;
        const bf16_t* TA = A + (long)bmT * K;
        const bf16_t* TB = B + (long)(NTB * 256) * K;   // rows 8192..8223
        bf16_t* At = &As[0][0][0];                      // 128x64 tile (16KB)
        bf16_t* Bt = &Bs[0][0][0];                      // 32x64 tile (4KB)
        f32x4 tacc[2];
        tacc[0] = (f32x4){0.f, 0.f, 0.f, 0.f};
        tacc[1] = (f32x4){0.f, 0.f, 0.f, 0.f};
        for (int k0 = 0; k0 < K; k0 += BK) {
            #pragma unroll
            for (int it = 0; it < 2; ++it) {
                const int s = it * 512 + tid;           // 1024 slots of 8
                const int row = s >> 3, c16 = s & 7;
                gload_lds16(TA + (long)row * K + k0 + c16 * 8, &At[s * 8]);
            }
            if (tid < 256) {
                const int row = tid >> 3, c16 = tid & 7;
                gload_lds16(TB + (long)row * K + k0 + c16 * 8, &Bt[tid * 8]);
            }
            __syncthreads();
            #pragma unroll
            for (int ks = 0; ks < 2; ++ks) {
                const int kc = (ks * 4 + l4) * 8;
                bf16x8 a = *reinterpret_cast<const bf16x8*>(&At[(wv * 16 + l15) * 64 + kc]);
                #pragma unroll
                for (int nj = 0; nj < 2; ++nj) {
                    bf16x8 bfr = *reinterpret_cast<const bf16x8*>(&Bt[(nj * 16 + l15) * 64 + kc]);
                    tacc[nj] = __builtin_amdgcn_mfma_f32_16x16x32_bf16(a, bfr, tacc[nj], 0, 0, 0);
                }
            }
            __syncthreads();
        }
        #pragma unroll
        for (int nj = 0; nj < 2; ++nj) {
            #pragma unroll
            for (int jj = 0; jj < 4; ++jj) {
                const long row = bmT + wv * 16 + l4 * 4 + jj;
                const int col = NTB * 256 + nj * 16 + l15;
                if (OBF16) ((bf16_t*)Cv)[row * ldc + col] = f2b(tacc[nj][jj]);
                else       ((float*)Cv)[row * ldc + col] = tacc[nj][jj];
            }
        }
        return;
    }

    const int bm = (wg / NTB) * 256;
    const int bn = (wg % NTB) * 256;
    const int wr = wv >> 2, wc = wv & 3;       // 2x4 wave grid

    f32x4 acc[8][4];
    #pragma unroll
    for (int i = 0; i < 8; ++i)
        #pragma unroll
        for (int j = 0; j < 4; ++j) acc[i][j] = (f32x4){0.f, 0.f, 0.f, 0.f};

    const bf16_t* Abase = A + (long)bm * K;
    const bf16_t* Bbase = B + (long)bn * K;

    auto stage_half = [&](int t, int buf, int kh) {
        #pragma unroll
        for (int it = 0; it < 2; ++it) {
            const int s   = it * 512 + tid;          // 0..1023
            const int row = s >> 2;                  // 0..255
            const int jp  = s & 3;                   // physical chunk in half
            const int jl  = jp ^ ((row >> 1) & 3);   // logical chunk in half
            const long go = (long)row * K + t * BK + kh * 32 + jl * 8;
            gload_lds16(Abase + go, &As[buf][kh][s * 8]);
            gload_lds16(Bbase + go, &Bs[buf][kh][s * 8]);
        }
    };
    auto rdA = [&](int buf, int kh, int row) {
        const int jp = l4 ^ ((row >> 1) & 3);
        return *reinterpret_cast<const bf16x8*>(&As[buf][kh][(row * 4 + jp) * 8]);
    };
    auto rdB = [&](int buf, int kh, int row) {
        const int jp = l4 ^ ((row >> 1) & 3);
        return *reinterpret_cast<const bf16x8*>(&Bs[buf][kh][(row * 4 + jp) * 8]);
    };

    stage_half(0, 0, 0);
    stage_half(0, 0, 1);
    asm volatile("s_waitcnt vmcnt(4)" ::: "memory");   // K-half0 of tile 0 landed
    __builtin_amdgcn_s_barrier();

    for (int t = 0; t < NT; ++t) {
        const int cur = t & 1;
        bf16x8 bfr[4], af[4];
        if (t + 1 < NT) stage_half(t + 1, cur ^ 1, 0);
        // K-half 0: qm=0 then qm=1
        #pragma unroll
        for (int ni = 0; ni < 4; ++ni) bfr[ni] = rdB(cur, 0, wc * 64 + ni * 16 + l15);
        #pragma unroll
        for (int mi = 0; mi < 4; ++mi) af[mi] = rdA(cur, 0, wr * 128 + mi * 16 + l15);
        __builtin_amdgcn_s_setprio(1);
        #pragma unroll
        for (int mi = 0; mi < 4; ++mi)
            #pragma unroll
            for (int ni = 0; ni < 4; ++ni)
                acc[mi][ni] = __builtin_amdgcn_mfma_f32_16x16x32_bf16(
                    af[mi], bfr[ni], acc[mi][ni], 0, 0, 0);
        __builtin_amdgcn_s_setprio(0);
        #pragma unroll
        for (int mi = 0; mi < 4; ++mi) af[mi] = rdA(cur, 0, wr * 128 + 64 + mi * 16 + l15);
        __builtin_amdgcn_s_setprio(1);
        #pragma unroll
        for (int mi = 0; mi < 4; ++mi)
            #pragma unroll
            for (int ni = 0; ni < 4; ++ni)
                acc[4 + mi][ni] = __builtin_amdgcn_mfma_f32_16x16x32_bf16(
                    af[mi], bfr[ni], acc[4 + mi][ni], 0, 0, 0);
        __builtin_amdgcn_s_setprio(0);
        if (t + 1 < NT) {
            stage_half(t + 1, cur ^ 1, 1);
            asm volatile("s_waitcnt vmcnt(8)" ::: "memory");   // K1(t) landed
        } else {
            asm volatile("s_waitcnt vmcnt(0)" ::: "memory");
        }
        __builtin_amdgcn_s_barrier();
        // K-half 1: qm=0 then qm=1
        #pragma unroll
        for (int ni = 0; ni < 4; ++ni) bfr[ni] = rdB(cur, 1, wc * 64 + ni * 16 + l15);
        #pragma unroll
        for (int mi = 0; mi < 4; ++mi) af[mi] = rdA(cur, 1, wr * 128 + mi * 16 + l15);
        __builtin_amdgcn_s_setprio(1);
        #pragma unroll
        for (int mi = 0; mi < 4; ++mi)
            #pragma unroll
            for (int ni = 0; ni < 4; ++ni)
                acc[mi][ni] = __builtin_amdgcn_mfma_f32_16x16x32_bf16(
                    af[mi], bfr[ni], acc[mi][ni], 0, 0, 0);
        __builtin_amdgcn_s_setprio(0);
        #pragma unroll
        for (int mi = 0; mi < 4; ++mi) af[mi] = rdA(cur, 1, wr * 128 + 64 + mi * 16 + l15);
        __builtin_amdgcn_s_setprio(1);
        #pragma unroll
        for (int mi = 0; mi < 4; ++mi)
            #pragma unroll
            for (int ni = 0; ni < 4; ++ni)
                acc[4 + mi][ni] = __builtin_amdgcn_mfma_f32_16x16x32_bf16(
                    af[mi], bfr[ni], acc[4 + mi][ni], 0, 0, 0);
        __builtin_amdgcn_s_setprio(0);
        if (t + 1 < NT) { asm volatile("s_waitcnt vmcnt(4)" ::: "memory"); }
        __builtin_amdgcn_s_barrier();
    }

    #pragma unroll
    for (int mf = 0; mf < 8; ++mf) {
        const long grow0 = bm + wr * 128 + mf * 16 + l4 * 4;
        #pragma unroll
        for (int ni = 0; ni < 4; ++ni) {
            const int gcol = bn + wc * 64 + ni * 16 + l15;
            #pragma unroll
            for (int j = 0; j < 4; ++j) {
                if (OBF16)
                    ((bf16_t*)Cv)[(grow0 + j) * ldc + gcol] = f2b(acc[mf][ni][j]);
                else
                    ((float*)Cv)[(grow0 + j) * ldc + gcol] = acc[mf][ni][j];
            }
        }
    }
}

// ---------------------------------------------------------------------------
// Fused causal depthwise conv (K=4), 4 consecutive columns, reading bf16 xBCzA.
// ---------------------------------------------------------------------------
__device__ __forceinline__ float4 conv4v(const bf16_t* __restrict__ xb, long m, int l,
                                         int col, const float* __restrict__ cw,
                                         const float* __restrict__ cbv)
{
    float4 acc = *reinterpret_cast<const float4*>(cbv + col);
    float4 wc0 = *reinterpret_cast<const float4*>(cw + (long)col * 4);
    float4 wc1 = *reinterpret_cast<const float4*>(cw + (long)col * 4 + 4);
    float4 wc2 = *reinterpret_cast<const float4*>(cw + (long)col * 4 + 8);
    float4 wc3 = *reinterpret_cast<const float4*>(cw + (long)col * 4 + 12);
    const float t0[4] = {wc0.x, wc0.y, wc0.z, wc0.w};
    const float t1[4] = {wc1.x, wc1.y, wc1.z, wc1.w};
    const float t2[4] = {wc2.x, wc2.y, wc2.z, wc2.w};
    const float t3[4] = {wc3.x, wc3.y, wc3.z, wc3.w};
    #pragma unroll
    for (int tap = 0; tap < 4; ++tap) {
        if (l - 3 + tap < 0) continue;
        const bf16_t* p = xb + (m - 3 + tap) * (long)IN_OUT + col;
        ushort4 v = *reinterpret_cast<const ushort4*>(p);
        acc.x = fmaf(b2f(v.x), t0[tap], acc.x);
        acc.y = fmaf(b2f(v.y), t1[tap], acc.y);
        acc.z = fmaf(b2f(v.z), t2[tap], acc.z);
        acc.w = fmaf(b2f(v.w), t3[tap], acc.w);
    }
    return acc;
}

// ---------------------------------------------------------------------------
// Phase A (MFMA): 512 threads / 8 waves (4 row-groups x 2 col-halves).
// ---------------------------------------------------------------------------
template<bool EXP>
__global__ __launch_bounds__(512, 4) void ssd_states(const bf16_t* __restrict__ xb,
                                                     const float* __restrict__ cw,
                                                     const float* __restrict__ cbv,
                                                     bf16_t* __restrict__ states,
                                                     float* __restrict__ cumbuf,
                                                     float* __restrict__ cdecay,
                                                     bf16_t* __restrict__ xtg,
                                                     bf16_t* __restrict__ bg)
{
    const int h = blockIdx.x, c = blockIdx.y, b = blockIdx.z;
    __shared__ bf16_t sx [128 * 64];
    __shared__ bf16_t sBr[128 * 64];
    __shared__ bf16_t sXT[64 * 128];
    __shared__ bf16_t sBT[64 * 128];
    __shared__ float  cum[CHUNK];
    __shared__ float  w0tot;
    const int t = threadIdx.x;
    const long mbase = (long)b * SEQ + (long)c * CHUNK;
    const long cb = ((long)b * NCHUNK + c) * N_QK + h;

    float v = 0.f;
    if (t < CHUNK) {
        const float a = b2f(xb[(mbase + t) * (long)IN_OUT + (CONV_DIM + D_INNER) + h]);
        v = -((a > 20.f) ? a : log1pf(expf(a)));
        #pragma unroll
        for (int s = 1; s < 64; s <<= 1) {
            const float u2 = __shfl_up(v, s, 64);
            if ((t & 63) >= s) v += u2;
        }
        if (t == 63) w0tot = v;
    }
    for (int idx = t; idx < CHUNK * 16; idx += 512) {
        const int k = idx >> 4, q4 = (idx & 15) * 4;
        const long m = mbase + k;
        const int l = (int)(m & (SEQ - 1));
        float4 xv = conv4v(xb, m, l, h * 64 + q4, cw, cbv);
        float4 bv = conv4v(xb, m, l, D_INNER + h * 64 + q4, cw, cbv);
        store4b(&sx [SWZ64(k, q4)], xv);
        store4b(&sBr[SWZ64(k, q4)], bv);
    }
    __syncthreads();
    if (t >= 64 && t < CHUNK) v += w0tot;
    if (t < CHUNK) cum[t] = v;
    __syncthreads();
    const float clast = cum[CHUNK - 1];
    {
        const int j = t & 127;
        const int c8b = (t >> 7) * 2;
        const float ej = __expf(clast - cum[j]);
        #pragma unroll
        for (int it = 0; it < 2; ++it) {
            const int c8 = c8b + it;
            bf16x8 xv = *reinterpret_cast<const bf16x8*>(&sx [SWZ64(j, c8 * 8)]);
            bf16x8 bv = *reinterpret_cast<const bf16x8*>(&sBr[SWZ64(j, c8 * 8)]);
            #pragma unroll
            for (int e = 0; e < 8; ++e) {
                sXT[SWZ128(c8 * 8 + e, j)] = xv[e];
                sBT[SWZ128(c8 * 8 + e, j)] = f2b(b2f((bf16_t)bv[e]) * ej);
            }
        }
    }
    __syncthreads();

    const int lane = t & 63, wv = t >> 6;       // wv 0..7
    const int l15 = lane & 15, l4 = lane >> 4;
    const int prow  = (wv & 3) * 16;
    const int nbase = (wv >> 2) * 2;
    f32x4 acc[2];
    acc[0] = (f32x4){0.f, 0.f, 0.f, 0.f};
    acc[1] = (f32x4){0.f, 0.f, 0.f, 0.f};
    #pragma unroll
    for (int ks = 0; ks < 4; ++ks) {
        const int kc = ks * 32 + l4 * 8;
        bf16x8 af = *reinterpret_cast<const bf16x8*>(&sXT[SWZ128(prow + l15, kc)]);
        #pragma unroll
        for (int nj = 0; nj < 2; ++nj) {
            bf16x8 bf = *reinterpret_cast<const bf16x8*>(&sBT[SWZ128((nbase + nj) * 16 + l15, kc)]);
            acc[nj] = __builtin_amdgcn_mfma_f32_16x16x32_bf16(af, bf, acc[nj], 0, 0, 0);
        }
    }
    #pragma unroll
    for (int nj = 0; nj < 2; ++nj) {
        #pragma unroll
        for (int jj = 0; jj < 4; ++jj) {
            const int p = prow + l4 * 4 + jj;
            states[cb * 4096 + SWZ64(p, (nbase + nj) * 16 + l15)] = f2b(acc[nj][jj]);
        }
    }
    if constexpr (EXP) {
        #pragma unroll
        for (int it = 0; it < 2; ++it) {
            const int s = it * 512 + t;
            *reinterpret_cast<bf16x8*>(xtg + cb * 8192 + s * 8) =
                *reinterpret_cast<const bf16x8*>(&sXT[s * 8]);
            *reinterpret_cast<bf16x8*>(bg + cb * 8192 + s * 8) =
                *reinterpret_cast<const bf16x8*>(&sBr[s * 8]);
        }
    }
    if (t < CHUNK) cumbuf[cb * CHUNK + t] = cum[t];
    if (t == 0)   cdecay[cb] = __expf(clast);
}

// ---------------------------------------------------------------------------
// Phase B: inter-chunk scan, LDS-staged.
// ---------------------------------------------------------------------------
__global__ __launch_bounds__(256) void ssd_scan(bf16_t* __restrict__ states,
                                                const float* __restrict__ cdecay)
{
    const int bid = blockIdx.x;
    const int bh = bid >> 2, q = bid & 3;
    const int b = bh >> 5, h = bh & 31;
    const int t = threadIdx.x;
    __shared__ bf16_t sst[NCHUNK * 1024];   // 64 KiB
    __shared__ float  scd[NCHUNK];
    if (t < NCHUNK) scd[t] = cdecay[((long)b * NCHUNK + t) * N_QK + h];
    #pragma unroll
    for (int it = 0; it < 16; ++it) {
        const int slot = it * 256 + t;
        const int c = slot >> 7, off = (slot & 127) * 8;
        const long g = (((long)b * NCHUNK + c) * N_QK + h) * 4096 + q * 1024 + off;
        gload_lds16(states + g, &sst[slot * 8]);
    }
    __syncthreads();
    float4 carry = make_float4(0.f, 0.f, 0.f, 0.f);
    for (int c = 0; c < NCHUNK; ++c) {
        ushort4* p = reinterpret_cast<ushort4*>(&sst[c * 1024 + t * 4]);
        const ushort4 su = *p;
        ushort4 pv;
        pv.x = f2b(carry.x); pv.y = f2b(carry.y);
        pv.z = f2b(carry.z); pv.w = f2b(carry.w);
        *p = pv;
        const float cd = scd[c];
        carry.x = fmaf(carry.x, cd, b2f(su.x));
        carry.y = fmaf(carry.y, cd, b2f(su.y));
        carry.z = fmaf(carry.z, cd, b2f(su.z));
        carry.w = fmaf(carry.w, cd, b2f(su.w));
    }
    __syncthreads();
    #pragma unroll
    for (int it = 0; it < 16; ++it) {
        const int slot = it * 256 + t;
        const int c = slot >> 7, off = (slot & 127) * 8;
        const long g = (((long)b * NCHUNK + c) * N_QK + h) * 4096 + q * 1024 + off;
        *reinterpret_cast<bf16x8*>(states + g) =
            *reinterpret_cast<const bf16x8*>(&sst[slot * 8]);
    }
}

// ---------------------------------------------------------------------------
// Phase C (MFMA): 512 threads / 8 waves, each owning 16 output rows.
// ---------------------------------------------------------------------------
template<bool EXP>
__global__ __launch_bounds__(512, 4) void ssd_out(const bf16_t* __restrict__ xb,
                                                  const float* __restrict__ cumbuf,
                                                  const bf16_t* __restrict__ prevst,
                                                  const float* __restrict__ Dvec,
                                                  const float* __restrict__ zbias,
                                                  const float* __restrict__ cw,
                                                  const float* __restrict__ cbv,
                                                  const bf16_t* __restrict__ xtg,
                                                  const bf16_t* __restrict__ bg,
                                                  bf16_t* __restrict__ yz)
{
    const int h = blockIdx.x, c = blockIdx.y, b = blockIdx.z;
    __shared__ bf16_t sC[128 * 64];
    __shared__ bf16_t sB[128 * 64];
    __shared__ bf16_t sXQ[128 * 64];   // x tile (FB) / Q scratch
    __shared__ bf16_t sXT[64 * 128];   // x^T
    __shared__ bf16_t sP[64 * 64];     // prev state (bf16, SWZ64-physical)
    __shared__ float  cum[CHUNK];
    const int t = threadIdx.x;
    const long mbase = (long)b * SEQ + (long)c * CHUNK;
    const long cb = ((long)b * NCHUNK + c) * N_QK + h;
    if (t < CHUNK) cum[t] = cumbuf[cb * CHUNK + t];
    gload_lds16(prevst + cb * 4096 + t * 8, &sP[t * 8]);
    if constexpr (EXP) {
        #pragma unroll
        for (int it = 0; it < 2; ++it) {
            const int s = it * 512 + t;
            gload_lds16(bg  + cb * 8192 + s * 8, &sB [s * 8]);
            gload_lds16(xtg + cb * 8192 + s * 8, &sXT[s * 8]);
        }
        for (int idx = t; idx < CHUNK * 16; idx += 512) {
            const int k = idx >> 4, q4 = (idx & 15) * 4;
            const long m = mbase + k;
            const int l = (int)(m & (SEQ - 1));
            float4 cv = conv4v(xb, m, l, 2 * D_INNER + h * 64 + q4, cw, cbv);
            store4b(&sC[SWZ64(k, q4)], cv);
        }
        __syncthreads();
    } else {
        for (int idx = t; idx < CHUNK * 16; idx += 512) {
            const int k = idx >> 4, q4 = (idx & 15) * 4;
            const long m = mbase + k;
            const int l = (int)(m & (SEQ - 1));
            float4 xv = conv4v(xb, m, l, h * 64 + q4, cw, cbv);
            float4 bv = conv4v(xb, m, l, D_INNER + h * 64 + q4, cw, cbv);
            float4 cv = conv4v(xb, m, l, 2 * D_INNER + h * 64 + q4, cw, cbv);
            store4b(&sXQ[SWZ64(k, q4)], xv);
            store4b(&sB [SWZ64(k, q4)], bv);
            store4b(&sC [SWZ64(k, q4)], cv);
        }
        __syncthreads();
        {
            const int j = t & 127;
            const int c8b = (t >> 7) * 2;
            #pragma unroll
            for (int it = 0; it < 2; ++it) {
                const int c8 = c8b + it;
                bf16x8 v = *reinterpret_cast<const bf16x8*>(&sXQ[SWZ64(j, c8 * 8)]);
                #pragma unroll
                for (int e = 0; e < 8; ++e) sXT[SWZ128(c8 * 8 + e, j)] = v[e];
            }
        }
        __syncthreads();
    }

    const int lane = t & 63, wv = t >> 6;       // wv 0..7
    const int w16 = wv * 16, l15 = lane & 15, l4 = lane >> 4;
    bf16_t* sQ = sXQ;

    f32x4 yac[4], iac[4];
    #pragma unroll
    for (int np = 0; np < 4; ++np) {
        yac[np] = (f32x4){0.f, 0.f, 0.f, 0.f};
        iac[np] = (f32x4){0.f, 0.f, 0.f, 0.f};
    }

    #pragma unroll
    for (int H = 0; H < 2; ++H) {
        if (H == 1 && wv < 4) break;
        const int j0 = H * 64;
        f32x4 sac[4];
        #pragma unroll
        for (int nj = 0; nj < 4; ++nj) sac[nj] = (f32x4){0.f, 0.f, 0.f, 0.f};
        #pragma unroll
        for (int kk = 0; kk < 2; ++kk) {
            const int kc = kk * 32 + l4 * 8;
            bf16x8 af0 = *reinterpret_cast<const bf16x8*>(&sC[SWZ64(w16 + l15, kc)]);
            #pragma unroll
            for (int nj = 0; nj < 4; ++nj) {
                if (j0 + nj * 16 <= w16 + 15) {
                    bf16x8 bfj = *reinterpret_cast<const bf16x8*>(&sB[SWZ64(j0 + nj * 16 + l15, kc)]);
                    sac[nj] = __builtin_amdgcn_mfma_f32_16x16x32_bf16(af0, bfj, sac[nj], 0, 0, 0);
                }
            }
        }
        #pragma unroll
        for (int nj = 0; nj < 4; ++nj) {
            const int jcol = nj * 16 + l15;
            const int jg = j0 + jcol;
            #pragma unroll
            for (int jj = 0; jj < 4; ++jj) {
                const int i = w16 + l4 * 4 + jj;
                const float q = (jg <= i) ? __expf(cum[i] - cum[jg]) * sac[nj][jj] : 0.f;
                sQ[SWZ64(i, jcol)] = f2b(q);
            }
        }
        #pragma unroll
        for (int kk = 0; kk < 2; ++kk) {
            const int kc = kk * 32 + l4 * 8;
            bf16x8 qa = *reinterpret_cast<const bf16x8*>(&sQ[SWZ64(w16 + l15, kc)]);
            #pragma unroll
            for (int np = 0; np < 4; ++np) {
                bf16x8 xf = *reinterpret_cast<const bf16x8*>(&sXT[SWZ128(np * 16 + l15, j0 + kc)]);
                yac[np] = __builtin_amdgcn_mfma_f32_16x16x32_bf16(qa, xf, yac[np], 0, 0, 0);
            }
        }
    }
    #pragma unroll
    for (int kk = 0; kk < 2; ++kk) {
        const int kc = kk * 32 + l4 * 8;
        bf16x8 cf = *reinterpret_cast<const bf16x8*>(&sC[SWZ64(w16 + l15, kc)]);
        #pragma unroll
        for (int np = 0; np < 4; ++np) {
            bf16x8 pf = *reinterpret_cast<const bf16x8*>(&sP[SWZ64(np * 16 + l15, kc)]);
            iac[np] = __builtin_amdgcn_mfma_f32_16x16x32_bf16(cf, pf, iac[np], 0, 0, 0);
        }
    }
    const float dh = Dvec[h];
    #pragma unroll
    for (int jj = 0; jj < 4; ++jj) {
        const int i = w16 + l4 * 4 + jj;
        const float ei = __expf(cum[i]);
        const long m = mbase + i;
        const bf16_t* zr = xb + m * (long)IN_OUT + CONV_DIM + h * 64;
        bf16_t* orow = yz + m * (long)D_INNER + h * 64;
        #pragma unroll
        for (int np = 0; np < 4; ++np) {
            const int p = np * 16 + l15;
            const float xval = b2f(sXT[SWZ128(p, i)]);
            const float y = yac[np][jj] + ei * iac[np][jj] + dh * xval;
            const float zv = b2f(zr[p]) + zbias[h * 64 + p];
            const float s = zv / (1.f + __expf(-zv));
            orow[p] = f2b(y * s);
        }
    }
}

// ---------------------------------------------------------------------------
extern "C" void kernel_launch(void* const* d_in, const int* in_sizes, int n_in,
                              void* d_out, int out_size, void* d_ws, size_t ws_size,
                              hipStream_t stream)
{
    const float* u      = (const float*)d_in[0];
    const float* W_in   = (const float*)d_in[1];
    const float* conv_w = (const float*)d_in[2];
    const float* conv_b = (const float*)d_in[3];
    const float* Dv     = (const float*)d_in[4];
    const float* z_bias = (const float*)d_in[5];
    const float* W_out  = (const float*)d_in[6];
    float* out = (float*)d_out;

    char* w = (char*)d_ws;
    bf16_t* xbcza = (bf16_t*)w;  w += (long)M_ROWS * IN_OUT * 2;   // 128.5 MiB
    bf16_t* wob   = (bf16_t*)w;  w += (long)2048 * 2048 * 2;       //   8 MiB
    char* ureg = w;  w += 67239936;                                 // 64.1 MiB union
    bf16_t* ub  = (bf16_t*)ureg;                                    // 32 MiB (phase 1)
    bf16_t* wib = (bf16_t*)(ureg + (long)M_ROWS * D_MODEL * 2);     // 32.125 MiB (phase 1)
    bf16_t* yzb = (bf16_t*)ureg;                                    // 32 MiB (phase 2)
    float*  cumb   = (float*)(ureg + (long)M_ROWS * D_INNER * 2);   //  1 MiB
    bf16_t* states = (bf16_t*)(cumb + (long)BATCH * NCHUNK * N_QK * CHUNK); // 16 MiB
    float*  cdec   = (float*)(states + (long)BATCH * NCHUNK * N_QK * 4096); //  8 KiB
    const long base_bytes = (long)(w - (char*)d_ws);
    const long exp_bytes  = 2L * 2048 * 8192 * 2;                   // xtg + bg
    const bool use_exp = ((long)ws_size >= base_bytes + exp_bytes);
    bf16_t* xtg = (bf16_t*)w;
    bf16_t* bg  = xtg + (long)2048 * 8192;

    // fused fp32->bf16 conversions (u, W_in, W_out)
    {
        const long n0 = (long)M_ROWS * D_MODEL;
        const long n1 = (long)IN_OUT * D_MODEL;
        const long n2 = (long)D_MODEL * D_INNER;
        const long nb = ((n0 + n1 + n2) / 4 + 255) / 256;
        f2b3_kernel<<<(int)nb, 256, 0, stream>>>(u, ub, n0, W_in, wib, n1, W_out, wob, n2);
    }

    // GEMM1: cols [0, 8192) main (1024 wgs) + A_log tail (64 wgs), one dispatch
    gemm256<32, D_MODEL, true, true><<<(M_ROWS / 256) * 32 + 64, 512, 0, stream>>>(
        ub, wib, xbcza, IN_OUT);

    if (use_exp) {
        ssd_states<true><<<dim3(N_QK, NCHUNK, BATCH), 512, 0, stream>>>(
            xbcza, conv_w, conv_b, states, cumb, cdec, xtg, bg);
        ssd_scan<<<BATCH * N_QK * 4, 256, 0, stream>>>(states, cdec);
        ssd_out<true><<<dim3(N_QK, NCHUNK, BATCH), 512, 0, stream>>>(
            xbcza, cumb, states, Dv, z_bias, conv_w, conv_b, xtg, bg, yzb);
    } else {
        ssd_states<false><<<dim3(N_QK, NCHUNK, BATCH), 512, 0, stream>>>(
            xbcza, conv_w, conv_b, states, cumb, cdec, nullptr, nullptr);
        ssd_scan<<<BATCH * N_QK * 4, 256, 0, stream>>>(states, cdec);
        ssd_out<false><<<dim3(N_QK, NCHUNK, BATCH), 512, 0, stream>>>(
            xbcza, cumb, states, Dv, z_bias, conv_w, conv_b, nullptr, nullptr, yzb);
    }

    // GEMM2: out = yz @ W_out^T  (8192 x 2048 x 2048), 256 wgs
    gemm256<8, D_INNER, false, false><<<(M_ROWS / 256) * 8, 512, 0, stream>>>(
        yzb, wob, out, D_MODEL);
}

// Round 15
// 730.775 us; speedup vs baseline: 1.0347x; 1.0347x over previous
//
#include <hip/hip_runtime.h>
#include <math.h>

#define D_MODEL  2048
#define D_INNER  2048
#define N_QK     32
#define N_V      32
#define D_STATE  64
#define D_CONV   4
#define CHUNK    128
#define CONV_DIM 6144      // D_INNER + 2*N_QK*D_STATE
#define IN_OUT   8224      // 2*D_INNER + 2*N_QK*D_STATE + N_V
#define BATCH    2
#define SEQ      4096
#define M_ROWS   (BATCH*SEQ)   // 8192
#define NCHUNK   (SEQ/CHUNK)   // 32

typedef unsigned short bf16_t;
typedef __attribute__((ext_vector_type(4))) float f32x4;
typedef __attribute__((ext_vector_type(8))) short bf16x8;

// swizzled row-major LDS index (elem units); XOR bits 3-5 spread rows over banks
#define SWZ64(r,c)  ((((r)*64)  + (c)) ^ (((r)&7)<<3))
#define SWZ128(r,c) ((((r)*128) + (c)) ^ (((r)&7)<<3))

__device__ __forceinline__ float b2f(bf16_t u) {
    union { unsigned int i; float f; } w; w.i = ((unsigned int)u) << 16; return w.f;
}
__device__ __forceinline__ bf16_t f2b(float f) {
    unsigned int x = __float_as_uint(f);
    return (bf16_t)((x + 0x7FFFu + ((x >> 16) & 1u)) >> 16);   // RNE
}
__device__ __forceinline__ void store4b(bf16_t* dst, float4 v) {
    ushort4 u; u.x = f2b(v.x); u.y = f2b(v.y); u.z = f2b(v.z); u.w = f2b(v.w);
    *reinterpret_cast<ushort4*>(dst) = u;
}

__device__ __forceinline__ void gload_lds16(const bf16_t* g, bf16_t* l) {
    __builtin_amdgcn_global_load_lds((const __attribute__((address_space(1))) void*)g,
                                     (__attribute__((address_space(3))) void*)l,
                                     16, 0, 0);
}

// ---------------------------------------------------------------------------
// fused fp32 -> bf16 convert (grid-stride, 2048 blocks)
// ---------------------------------------------------------------------------
__global__ __launch_bounds__(256) void f2b3_kernel(const float* __restrict__ a0, bf16_t* __restrict__ o0, long n0,
                                                   const float* __restrict__ a1, bf16_t* __restrict__ o1, long n1,
                                                   const float* __restrict__ a2, bf16_t* __restrict__ o2, long n2)
{
    const long total = (n0 + n1 + n2) >> 2;
    for (long s = (long)blockIdx.x * 256 + threadIdx.x; s < total; s += (long)gridDim.x * 256) {
        long i = s << 2;
        const float* in; bf16_t* out;
        if (i < n0)           { in = a0 + i; out = o0 + i; }
        else if (i < n0 + n1) { i -= n0; in = a1 + i; out = o1 + i; }
        else                  { i -= n0 + n1; in = a2 + i; out = o2 + i; }
        float4 v = *reinterpret_cast<const float4*>(in);
        ushort4 o;
        o.x = f2b(v.x); o.y = f2b(v.y); o.z = f2b(v.z); o.w = f2b(v.w);
        *reinterpret_cast<ushort4*>(out) = o;
    }
}

// ---------------------------------------------------------------------------
// 256x256 bf16 MFMA NT-GEMM, K-half counted-vmcnt pipeline, 2 barriers/tile.
// (R12/R13-proven structure -- do not touch.)
// ---------------------------------------------------------------------------
template<int NTB, int K, bool OBF16>
__global__ __launch_bounds__(512, 2) void gemm256(const bf16_t* __restrict__ A,
                                                  const bf16_t* __restrict__ B,
                                                  void* __restrict__ Cv,
                                                  long ldc)
{
    constexpr int BK = 64;
    constexpr int NT = K / BK;
    __shared__ bf16_t As[2][2][8192];   // [buf][kh][1024 slots * 8 elems]
    __shared__ bf16_t Bs[2][2][8192];

    const int nwg = gridDim.x;
    const int bid = blockIdx.x;
    const int wg  = ((nwg & 7) == 0) ? ((bid & 7) * (nwg >> 3) + (bid >> 3)) : bid;
    const int bm = (wg / NTB) * 256;
    const int bn = (wg % NTB) * 256;

    const int tid  = threadIdx.x;
    const int lane = tid & 63;
    const int wv   = tid >> 6;
    const int wr   = wv >> 2, wc = wv & 3;       // 2x4 wave grid
    const int l15  = lane & 15, l4 = lane >> 4;

    f32x4 acc[8][4];
    #pragma unroll
    for (int i = 0; i < 8; ++i)
        #pragma unroll
        for (int j = 0; j < 4; ++j) acc[i][j] = (f32x4){0.f, 0.f, 0.f, 0.f};

    const bf16_t* Abase = A + (long)bm * K;
    const bf16_t* Bbase = B + (long)bn * K;

    auto stage_half = [&](int t, int buf, int kh) {
        #pragma unroll
        for (int it = 0; it < 2; ++it) {
            const int s   = it * 512 + tid;          // 0..1023
            const int row = s >> 2;                  // 0..255
            const int jp  = s & 3;                   // physical chunk in half
            const int jl  = jp ^ ((row >> 1) & 3);   // logical chunk in half
            const long go = (long)row * K + t * BK + kh * 32 + jl * 8;
            gload_lds16(Abase + go, &As[buf][kh][s * 8]);
            gload_lds16(Bbase + go, &Bs[buf][kh][s * 8]);
        }
    };
    auto rdA = [&](int buf, int kh, int row) {
        const int jp = l4 ^ ((row >> 1) & 3);
        return *reinterpret_cast<const bf16x8*>(&As[buf][kh][(row * 4 + jp) * 8]);
    };
    auto rdB = [&](int buf, int kh, int row) {
        const int jp = l4 ^ ((row >> 1) & 3);
        return *reinterpret_cast<const bf16x8*>(&Bs[buf][kh][(row * 4 + jp) * 8]);
    };

    stage_half(0, 0, 0);
    stage_half(0, 0, 1);
    asm volatile("s_waitcnt vmcnt(4)" ::: "memory");   // K-half0 of tile 0 landed
    __builtin_amdgcn_s_barrier();

    for (int t = 0; t < NT; ++t) {
        const int cur = t & 1;
        bf16x8 bfr[4], af[4];
        if (t + 1 < NT) stage_half(t + 1, cur ^ 1, 0);
        // K-half 0: qm=0 then qm=1
        #pragma unroll
        for (int ni = 0; ni < 4; ++ni) bfr[ni] = rdB(cur, 0, wc * 64 + ni * 16 + l15);
        #pragma unroll
        for (int mi = 0; mi < 4; ++mi) af[mi] = rdA(cur, 0, wr * 128 + mi * 16 + l15);
        __builtin_amdgcn_s_setprio(1);
        #pragma unroll
        for (int mi = 0; mi < 4; ++mi)
            #pragma unroll
            for (int ni = 0; ni < 4; ++ni)
                acc[mi][ni] = __builtin_amdgcn_mfma_f32_16x16x32_bf16(
                    af[mi], bfr[ni], acc[mi][ni], 0, 0, 0);
        __builtin_amdgcn_s_setprio(0);
        #pragma unroll
        for (int mi = 0; mi < 4; ++mi) af[mi] = rdA(cur, 0, wr * 128 + 64 + mi * 16 + l15);
        __builtin_amdgcn_s_setprio(1);
        #pragma unroll
        for (int mi = 0; mi < 4; ++mi)
            #pragma unroll
            for (int ni = 0; ni < 4; ++ni)
                acc[4 + mi][ni] = __builtin_amdgcn_mfma_f32_16x16x32_bf16(
                    af[mi], bfr[ni], acc[4 + mi][ni], 0, 0, 0);
        __builtin_amdgcn_s_setprio(0);
        if (t + 1 < NT) {
            stage_half(t + 1, cur ^ 1, 1);
            asm volatile("s_waitcnt vmcnt(8)" ::: "memory");   // K1(t) landed
        } else {
            asm volatile("s_waitcnt vmcnt(0)" ::: "memory");
        }
        __builtin_amdgcn_s_barrier();
        // K-half 1: qm=0 then qm=1
        #pragma unroll
        for (int ni = 0; ni < 4; ++ni) bfr[ni] = rdB(cur, 1, wc * 64 + ni * 16 + l15);
        #pragma unroll
        for (int mi = 0; mi < 4; ++mi) af[mi] = rdA(cur, 1, wr * 128 + mi * 16 + l15);
        __builtin_amdgcn_s_setprio(1);
        #pragma unroll
        for (int mi = 0; mi < 4; ++mi)
            #pragma unroll
            for (int ni = 0; ni < 4; ++ni)
                acc[mi][ni] = __builtin_amdgcn_mfma_f32_16x16x32_bf16(
                    af[mi], bfr[ni], acc[mi][ni], 0, 0, 0);
        __builtin_amdgcn_s_setprio(0);
        #pragma unroll
        for (int mi = 0; mi < 4; ++mi) af[mi] = rdA(cur, 1, wr * 128 + 64 + mi * 16 + l15);
        __builtin_amdgcn_s_setprio(1);
        #pragma unroll
        for (int mi = 0; mi < 4; ++mi)
            #pragma unroll
            for (int ni = 0; ni < 4; ++ni)
                acc[4 + mi][ni] = __builtin_amdgcn_mfma_f32_16x16x32_bf16(
                    af[mi], bfr[ni], acc[4 + mi][ni], 0, 0, 0);
        __builtin_amdgcn_s_setprio(0);
        if (t + 1 < NT) { asm volatile("s_waitcnt vmcnt(4)" ::: "memory"); }
        __builtin_amdgcn_s_barrier();
    }

    #pragma unroll
    for (int mf = 0; mf < 8; ++mf) {
        const long grow0 = bm + wr * 128 + mf * 16 + l4 * 4;
        #pragma unroll
        for (int ni = 0; ni < 4; ++ni) {
            const int gcol = bn + wc * 64 + ni * 16 + l15;
            #pragma unroll
            for (int j = 0; j < 4; ++j) {
                if (OBF16)
                    ((bf16_t*)Cv)[(grow0 + j) * ldc + gcol] = f2b(acc[mf][ni][j]);
                else
                    ((float*)Cv)[(grow0 + j) * ldc + gcol] = acc[mf][ni][j];
            }
        }
    }
}

// ---------------------------------------------------------------------------
// 128x128 m97-style MFMA GEMM (A_log 32-col tail), ldc-param.
// ---------------------------------------------------------------------------
template<int N, int K, bool OBF16>
__global__ __launch_bounds__(256) void gemm_mfma(const bf16_t* __restrict__ A,
                                                 const bf16_t* __restrict__ B,
                                                 void* __restrict__ Cv,
                                                 long ldc)
{
    constexpr int BM = 128, BN = 128, BK = 64;
    constexpr int NTB = (N + BN - 1) / BN;
    __shared__ bf16_t As[BM * BK];
    __shared__ bf16_t Bs[BM * BK];

    const int nwg = gridDim.x;
    const int bid = blockIdx.x;
    const int wg  = ((nwg & 7) == 0) ? ((bid & 7) * (nwg >> 3) + (bid >> 3)) : bid;
    const int bm = (wg / NTB) * BM;
    const int bn = (wg % NTB) * BN;

    const int tid  = threadIdx.x;
    const int lane = tid & 63;
    const int wv   = tid >> 6;
    const int wr   = wv >> 1, wc = wv & 1;

    f32x4 acc[4][4];
    #pragma unroll
    for (int i = 0; i < 4; ++i)
        #pragma unroll
        for (int j = 0; j < 4; ++j) acc[i][j] = (f32x4){0.f, 0.f, 0.f, 0.f};

    for (int k0 = 0; k0 < K; k0 += BK) {
        #pragma unroll
        for (int it = 0; it < 4; ++it) {
            const int seg = it * 256 + tid;
            const int row = seg >> 3, c16 = seg & 7;
            gload_lds16(A + (long)(bm + row) * K + k0 + c16 * 8,
                        &As[row * BK + c16 * 8]);
            int brow = bn + row;
            if constexpr (N % BN != 0) brow = min(brow, N - 1);
            gload_lds16(B + (long)brow * K + k0 + c16 * 8,
                        &Bs[row * BK + c16 * 8]);
        }
        __syncthreads();
        #pragma unroll
        for (int kk = 0; kk < 2; ++kk) {
            bf16x8 af[4], bfr[4];
            const int kc = kk * 32 + (lane >> 4) * 8;
            #pragma unroll
            for (int mi = 0; mi < 4; ++mi) {
                const int row = wr * 64 + mi * 16 + (lane & 15);
                af[mi] = *reinterpret_cast<const bf16x8*>(&As[row * BK + kc]);
            }
            #pragma unroll
            for (int ni = 0; ni < 4; ++ni) {
                const int row = wc * 64 + ni * 16 + (lane & 15);
                bfr[ni] = *reinterpret_cast<const bf16x8*>(&Bs[row * BK + kc]);
            }
            #pragma unroll
            for (int mi = 0; mi < 4; ++mi)
                #pragma unroll
                for (int ni = 0; ni < 4; ++ni)
                    acc[mi][ni] = __builtin_amdgcn_mfma_f32_16x16x32_bf16(
                        af[mi], bfr[ni], acc[mi][ni], 0, 0, 0);
        }
        __syncthreads();
    }

    #pragma unroll
    for (int mi = 0; mi < 4; ++mi) {
        const long row0 = bm + wr * 64 + mi * 16 + ((lane >> 4) << 2);
        #pragma unroll
        for (int ni = 0; ni < 4; ++ni) {
            const int col = bn + wc * 64 + ni * 16 + (lane & 15);
            if (N % BN != 0 && col >= N) continue;
            #pragma unroll
            for (int j = 0; j < 4; ++j) {
                if (OBF16)
                    ((bf16_t*)Cv)[(row0 + j) * ldc + col] = f2b(acc[mi][ni][j]);
                else
                    ((float*)Cv)[(row0 + j) * ldc + col] = acc[mi][ni][j];
            }
        }
    }
}

// ---------------------------------------------------------------------------
// Fused causal depthwise conv (K=4), 4 consecutive columns, reading bf16 xBCzA.
// ---------------------------------------------------------------------------
__device__ __forceinline__ float4 conv4v(const bf16_t* __restrict__ xb, long m, int l,
                                         int col, const float* __restrict__ cw,
                                         const float* __restrict__ cbv)
{
    float4 acc = *reinterpret_cast<const float4*>(cbv + col);
    float4 wc0 = *reinterpret_cast<const float4*>(cw + (long)col * 4);
    float4 wc1 = *reinterpret_cast<const float4*>(cw + (long)col * 4 + 4);
    float4 wc2 = *reinterpret_cast<const float4*>(cw + (long)col * 4 + 8);
    float4 wc3 = *reinterpret_cast<const float4*>(cw + (long)col * 4 + 12);
    const float t0[4] = {wc0.x, wc0.y, wc0.z, wc0.w};
    const float t1[4] = {wc1.x, wc1.y, wc1.z, wc1.w};
    const float t2[4] = {wc2.x, wc2.y, wc2.z, wc2.w};
    const float t3[4] = {wc3.x, wc3.y, wc3.z, wc3.w};
    #pragma unroll
    for (int tap = 0; tap < 4; ++tap) {
        if (l - 3 + tap < 0) continue;
        const bf16_t* p = xb + (m - 3 + tap) * (long)IN_OUT + col;
        ushort4 v = *reinterpret_cast<const ushort4*>(p);
        acc.x = fmaf(b2f(v.x), t0[tap], acc.x);
        acc.y = fmaf(b2f(v.y), t1[tap], acc.y);
        acc.z = fmaf(b2f(v.z), t2[tap], acc.z);
        acc.w = fmaf(b2f(v.w), t3[tap], acc.w);
    }
    return acc;
}

// ---------------------------------------------------------------------------
// Phase A (MFMA): 512 threads / 8 waves (4 row-groups x 2 col-halves).
// ---------------------------------------------------------------------------
template<bool EXP>
__global__ __launch_bounds__(512, 4) void ssd_states(const bf16_t* __restrict__ xb,
                                                     const float* __restrict__ cw,
                                                     const float* __restrict__ cbv,
                                                     bf16_t* __restrict__ states,
                                                     float* __restrict__ cumbuf,
                                                     float* __restrict__ cdecay,
                                                     bf16_t* __restrict__ xtg,
                                                     bf16_t* __restrict__ bg)
{
    const int h = blockIdx.x, c = blockIdx.y, b = blockIdx.z;
    __shared__ bf16_t sx [128 * 64];
    __shared__ bf16_t sBr[128 * 64];
    __shared__ bf16_t sXT[64 * 128];
    __shared__ bf16_t sBT[64 * 128];
    __shared__ float  cum[CHUNK];
    __shared__ float  w0tot;
    const int t = threadIdx.x;
    const long mbase = (long)b * SEQ + (long)c * CHUNK;
    const long cb = ((long)b * NCHUNK + c) * N_QK + h;

    float v = 0.f;
    if (t < CHUNK) {
        const float a = b2f(xb[(mbase + t) * (long)IN_OUT + (CONV_DIM + D_INNER) + h]);
        v = -((a > 20.f) ? a : log1pf(expf(a)));
        #pragma unroll
        for (int s = 1; s < 64; s <<= 1) {
            const float u2 = __shfl_up(v, s, 64);
            if ((t & 63) >= s) v += u2;
        }
        if (t == 63) w0tot = v;
    }
    for (int idx = t; idx < CHUNK * 16; idx += 512) {
        const int k = idx >> 4, q4 = (idx & 15) * 4;
        const long m = mbase + k;
        const int l = (int)(m & (SEQ - 1));
        float4 xv = conv4v(xb, m, l, h * 64 + q4, cw, cbv);
        float4 bv = conv4v(xb, m, l, D_INNER + h * 64 + q4, cw, cbv);
        store4b(&sx [SWZ64(k, q4)], xv);
        store4b(&sBr[SWZ64(k, q4)], bv);
    }
    __syncthreads();
    if (t >= 64 && t < CHUNK) v += w0tot;
    if (t < CHUNK) cum[t] = v;
    __syncthreads();
    const float clast = cum[CHUNK - 1];
    {
        const int j = t & 127;
        const int c8b = (t >> 7) * 2;
        const float ej = __expf(clast - cum[j]);
        #pragma unroll
        for (int it = 0; it < 2; ++it) {
            const int c8 = c8b + it;
            bf16x8 xv = *reinterpret_cast<const bf16x8*>(&sx [SWZ64(j, c8 * 8)]);
            bf16x8 bv = *reinterpret_cast<const bf16x8*>(&sBr[SWZ64(j, c8 * 8)]);
            #pragma unroll
            for (int e = 0; e < 8; ++e) {
                sXT[SWZ128(c8 * 8 + e, j)] = xv[e];
                sBT[SWZ128(c8 * 8 + e, j)] = f2b(b2f((bf16_t)bv[e]) * ej);
            }
        }
    }
    __syncthreads();

    const int lane = t & 63, wv = t >> 6;       // wv 0..7
    const int l15 = lane & 15, l4 = lane >> 4;
    const int prow  = (wv & 3) * 16;
    const int nbase = (wv >> 2) * 2;
    f32x4 acc[2];
    acc[0] = (f32x4){0.f, 0.f, 0.f, 0.f};
    acc[1] = (f32x4){0.f, 0.f, 0.f, 0.f};
    #pragma unroll
    for (int ks = 0; ks < 4; ++ks) {
        const int kc = ks * 32 + l4 * 8;
        bf16x8 af = *reinterpret_cast<const bf16x8*>(&sXT[SWZ128(prow + l15, kc)]);
        #pragma unroll
        for (int nj = 0; nj < 2; ++nj) {
            bf16x8 bf = *reinterpret_cast<const bf16x8*>(&sBT[SWZ128((nbase + nj) * 16 + l15, kc)]);
            acc[nj] = __builtin_amdgcn_mfma_f32_16x16x32_bf16(af, bf, acc[nj], 0, 0, 0);
        }
    }
    #pragma unroll
    for (int nj = 0; nj < 2; ++nj) {
        #pragma unroll
        for (int jj = 0; jj < 4; ++jj) {
            const int p = prow + l4 * 4 + jj;
            states[cb * 4096 + SWZ64(p, (nbase + nj) * 16 + l15)] = f2b(acc[nj][jj]);
        }
    }
    if constexpr (EXP) {
        #pragma unroll
        for (int it = 0; it < 2; ++it) {
            const int s = it * 512 + t;
            *reinterpret_cast<bf16x8*>(xtg + cb * 8192 + s * 8) =
                *reinterpret_cast<const bf16x8*>(&sXT[s * 8]);
            *reinterpret_cast<bf16x8*>(bg + cb * 8192 + s * 8) =
                *reinterpret_cast<const bf16x8*>(&sBr[s * 8]);
        }
    }
    if (t < CHUNK) cumbuf[cb * CHUNK + t] = cum[t];
    if (t == 0)   cdecay[cb] = __expf(clast);
}

// ---------------------------------------------------------------------------
// Phase B: inter-chunk scan, LDS-staged.
// ---------------------------------------------------------------------------
__global__ __launch_bounds__(256) void ssd_scan(bf16_t* __restrict__ states,
                                                const float* __restrict__ cdecay)
{
    const int bid = blockIdx.x;
    const int bh = bid >> 2, q = bid & 3;
    const int b = bh >> 5, h = bh & 31;
    const int t = threadIdx.x;
    __shared__ bf16_t sst[NCHUNK * 1024];   // 64 KiB
    __shared__ float  scd[NCHUNK];
    if (t < NCHUNK) scd[t] = cdecay[((long)b * NCHUNK + t) * N_QK + h];
    #pragma unroll
    for (int it = 0; it < 16; ++it) {
        const int slot = it * 256 + t;
        const int c = slot >> 7, off = (slot & 127) * 8;
        const long g = (((long)b * NCHUNK + c) * N_QK + h) * 4096 + q * 1024 + off;
        gload_lds16(states + g, &sst[slot * 8]);
    }
    __syncthreads();
    float4 carry = make_float4(0.f, 0.f, 0.f, 0.f);
    for (int c = 0; c < NCHUNK; ++c) {
        ushort4* p = reinterpret_cast<ushort4*>(&sst[c * 1024 + t * 4]);
        const ushort4 su = *p;
        ushort4 pv;
        pv.x = f2b(carry.x); pv.y = f2b(carry.y);
        pv.z = f2b(carry.z); pv.w = f2b(carry.w);
        *p = pv;
        const float cd = scd[c];
        carry.x = fmaf(carry.x, cd, b2f(su.x));
        carry.y = fmaf(carry.y, cd, b2f(su.y));
        carry.z = fmaf(carry.z, cd, b2f(su.z));
        carry.w = fmaf(carry.w, cd, b2f(su.w));
    }
    __syncthreads();
    #pragma unroll
    for (int it = 0; it < 16; ++it) {
        const int slot = it * 256 + t;
        const int c = slot >> 7, off = (slot & 127) * 8;
        const long g = (((long)b * NCHUNK + c) * N_QK + h) * 4096 + q * 1024 + off;
        *reinterpret_cast<bf16x8*>(states + g) =
            *reinterpret_cast<const bf16x8*>(&sst[slot * 8]);
    }
}

// ---------------------------------------------------------------------------
// Phase C (MFMA): 512 threads / 8 waves, each owning 16 output rows.
// ---------------------------------------------------------------------------
template<bool EXP>
__global__ __launch_bounds__(512, 4) void ssd_out(const bf16_t* __restrict__ xb,
                                                  const float* __restrict__ cumbuf,
                                                  const bf16_t* __restrict__ prevst,
                                                  const float* __restrict__ Dvec,
                                                  const float* __restrict__ zbias,
                                                  const float* __restrict__ cw,
                                                  const float* __restrict__ cbv,
                                                  const bf16_t* __restrict__ xtg,
                                                  const bf16_t* __restrict__ bg,
                                                  bf16_t* __restrict__ yz)
{
    const int h = blockIdx.x, c = blockIdx.y, b = blockIdx.z;
    __shared__ bf16_t sC[128 * 64];
    __shared__ bf16_t sB[128 * 64];
    __shared__ bf16_t sXQ[128 * 64];   // x tile (FB) / Q scratch
    __shared__ bf16_t sXT[64 * 128];   // x^T
    __shared__ bf16_t sP[64 * 64];     // prev state (bf16, SWZ64-physical)
    __shared__ float  cum[CHUNK];
    const int t = threadIdx.x;
    const long mbase = (long)b * SEQ + (long)c * CHUNK;
    const long cb = ((long)b * NCHUNK + c) * N_QK + h;
    if (t < CHUNK) cum[t] = cumbuf[cb * CHUNK + t];
    gload_lds16(prevst + cb * 4096 + t * 8, &sP[t * 8]);
    if constexpr (EXP) {
        #pragma unroll
        for (int it = 0; it < 2; ++it) {
            const int s = it * 512 + t;
            gload_lds16(bg  + cb * 8192 + s * 8, &sB [s * 8]);
            gload_lds16(xtg + cb * 8192 + s * 8, &sXT[s * 8]);
        }
        for (int idx = t; idx < CHUNK * 16; idx += 512) {
            const int k = idx >> 4, q4 = (idx & 15) * 4;
            const long m = mbase + k;
            const int l = (int)(m & (SEQ - 1));
            float4 cv = conv4v(xb, m, l, 2 * D_INNER + h * 64 + q4, cw, cbv);
            store4b(&sC[SWZ64(k, q4)], cv);
        }
        __syncthreads();
    } else {
        for (int idx = t; idx < CHUNK * 16; idx += 512) {
            const int k = idx >> 4, q4 = (idx & 15) * 4;
            const long m = mbase + k;
            const int l = (int)(m & (SEQ - 1));
            float4 xv = conv4v(xb, m, l, h * 64 + q4, cw, cbv);
            float4 bv = conv4v(xb, m, l, D_INNER + h * 64 + q4, cw, cbv);
            float4 cv = conv4v(xb, m, l, 2 * D_INNER + h * 64 + q4, cw, cbv);
            store4b(&sXQ[SWZ64(k, q4)], xv);
            store4b(&sB [SWZ64(k, q4)], bv);
            store4b(&sC [SWZ64(k, q4)], cv);
        }
        __syncthreads();
        {
            const int j = t & 127;
            const int c8b = (t >> 7) * 2;
            #pragma unroll
            for (int it = 0; it < 2; ++it) {
                const int c8 = c8b + it;
                bf16x8 v = *reinterpret_cast<const bf16x8*>(&sXQ[SWZ64(j, c8 * 8)]);
                #pragma unroll
                for (int e = 0; e < 8; ++e) sXT[SWZ128(c8 * 8 + e, j)] = v[e];
            }
        }
        __syncthreads();
    }

    const int lane = t & 63, wv = t >> 6;       // wv 0..7
    const int w16 = wv * 16, l15 = lane & 15, l4 = lane >> 4;
    bf16_t* sQ = sXQ;

    f32x4 yac[4], iac[4];
    #pragma unroll
    for (int np = 0; np < 4; ++np) {
        yac[np] = (f32x4){0.f, 0.f, 0.f, 0.f};
        iac[np] = (f32x4){0.f, 0.f, 0.f, 0.f};
    }

    #pragma unroll
    for (int H = 0; H < 2; ++H) {
        if (H == 1 && wv < 4) break;
        const int j0 = H * 64;
        f32x4 sac[4];
        #pragma unroll
        for (int nj = 0; nj < 4; ++nj) sac[nj] = (f32x4){0.f, 0.f, 0.f, 0.f};
        #pragma unroll
        for (int kk = 0; kk < 2; ++kk) {
            const int kc = kk * 32 + l4 * 8;
            bf16x8 af0 = *reinterpret_cast<const bf16x8*>(&sC[SWZ64(w16 + l15, kc)]);
            #pragma unroll
            for (int nj = 0; nj < 4; ++nj) {
                if (j0 + nj * 16 <= w16 + 15) {
                    bf16x8 bfj = *reinterpret_cast<const bf16x8*>(&sB[SWZ64(j0 + nj * 16 + l15, kc)]);
                    sac[nj] = __builtin_amdgcn_mfma_f32_16x16x32_bf16(af0, bfj, sac[nj], 0, 0, 0);
                }
            }
        }
        #pragma unroll
        for (int nj = 0; nj < 4; ++nj) {
            const int jcol = nj * 16 + l15;
            const int jg = j0 + jcol;
            #pragma unroll
            for (int jj = 0; jj < 4; ++jj) {
                const int i = w16 + l4 * 4 + jj;
                const float q = (jg <= i) ? __expf(cum[i] - cum[jg]) * sac[nj][jj] : 0.f;
                sQ[SWZ64(i, jcol)] = f2b(q);
            }
        }
        #pragma unroll
        for (int kk = 0; kk < 2; ++kk) {
            const int kc = kk * 32 + l4 * 8;
            bf16x8 qa = *reinterpret_cast<const bf16x8*>(&sQ[SWZ64(w16 + l15, kc)]);
            #pragma unroll
            for (int np = 0; np < 4; ++np) {
                bf16x8 xf = *reinterpret_cast<const bf16x8*>(&sXT[SWZ128(np * 16 + l15, j0 + kc)]);
                yac[np] = __builtin_amdgcn_mfma_f32_16x16x32_bf16(qa, xf, yac[np], 0, 0, 0);
            }
        }
    }
    #pragma unroll
    for (int kk = 0; kk < 2; ++kk) {
        const int kc = kk * 32 + l4 * 8;
        bf16x8 cf = *reinterpret_cast<const bf16x8*>(&sC[SWZ64(w16 + l15, kc)]);
        #pragma unroll
        for (int np = 0; np < 4; ++np) {
            bf16x8 pf = *reinterpret_cast<const bf16x8*>(&sP[SWZ64(np * 16 + l15, kc)]);
            iac[np] = __builtin_amdgcn_mfma_f32_16x16x32_bf16(cf, pf, iac[np], 0, 0, 0);
        }
    }
    const float dh = Dvec[h];
    #pragma unroll
    for (int jj = 0; jj < 4; ++jj) {
        const int i = w16 + l4 * 4 + jj;
        const float ei = __expf(cum[i]);
        const long m = mbase + i;
        const bf16_t* zr = xb + m * (long)IN_OUT + CONV_DIM + h * 64;
        bf16_t* orow = yz + m * (long)D_INNER + h * 64;
        #pragma unroll
        for (int np = 0; np < 4; ++np) {
            const int p = np * 16 + l15;
            const float xval = b2f(sXT[SWZ128(p, i)]);
            const float y = yac[np][jj] + ei * iac[np][jj] + dh * xval;
            const float zv = b2f(zr[p]) + zbias[h * 64 + p];
            const float s = zv / (1.f + __expf(-zv));
            orow[p] = f2b(y * s);
        }
    }
}

// ---------------------------------------------------------------------------
extern "C" void kernel_launch(void* const* d_in, const int* in_sizes, int n_in,
                              void* d_out, int out_size, void* d_ws, size_t ws_size,
                              hipStream_t stream)
{
    const float* u      = (const float*)d_in[0];
    const float* W_in   = (const float*)d_in[1];
    const float* conv_w = (const float*)d_in[2];
    const float* conv_b = (const float*)d_in[3];
    const float* Dv     = (const float*)d_in[4];
    const float* z_bias = (const float*)d_in[5];
    const float* W_out  = (const float*)d_in[6];
    float* out = (float*)d_out;

    char* w = (char*)d_ws;
    bf16_t* xbcza = (bf16_t*)w;  w += (long)M_ROWS * IN_OUT * 2;   // 128.5 MiB
    bf16_t* wob   = (bf16_t*)w;  w += (long)2048 * 2048 * 2;       //   8 MiB
    char* ureg = w;  w += 67239936;                                 // 64.1 MiB union
    bf16_t* ub  = (bf16_t*)ureg;                                    // 32 MiB (phase 1)
    bf16_t* wib = (bf16_t*)(ureg + (long)M_ROWS * D_MODEL * 2);     // 32.125 MiB (phase 1)
    bf16_t* yzb = (bf16_t*)ureg;                                    // 32 MiB (phase 2)
    float*  cumb   = (float*)(ureg + (long)M_ROWS * D_INNER * 2);   //  1 MiB
    bf16_t* states = (bf16_t*)(cumb + (long)BATCH * NCHUNK * N_QK * CHUNK); // 16 MiB
    float*  cdec   = (float*)(states + (long)BATCH * NCHUNK * N_QK * 4096); //  8 KiB
    const long base_bytes = (long)(w - (char*)d_ws);
    const long exp_bytes  = 2L * 2048 * 8192 * 2;                   // xtg + bg
    const bool use_exp = ((long)ws_size >= base_bytes + exp_bytes);
    bf16_t* xtg = (bf16_t*)w;
    bf16_t* bg  = xtg + (long)2048 * 8192;

    // fused fp32->bf16 conversions (u, W_in, W_out), grid-stride
    {
        const long n0 = (long)M_ROWS * D_MODEL;
        const long n1 = (long)IN_OUT * D_MODEL;
        const long n2 = (long)D_MODEL * D_INNER;
        f2b3_kernel<<<2048, 256, 0, stream>>>(u, ub, n0, W_in, wib, n1, W_out, wob, n2);
    }

    // GEMM1 main: cols [0, 8192), 1024 wgs, bm-major
    gemm256<32, D_MODEL, true><<<(M_ROWS / 256) * 32, 512, 0, stream>>>(
        ub, wib, xbcza, IN_OUT);
    // GEMM1 tail: cols [8192, 8224) (A_log)
    gemm_mfma<32, D_MODEL, true><<<(M_ROWS / 128), 256, 0, stream>>>(
        ub, wib + (long)8192 * D_MODEL, xbcza + 8192, IN_OUT);

    if (use_exp) {
        ssd_states<true><<<dim3(N_QK, NCHUNK, BATCH), 512, 0, stream>>>(
            xbcza, conv_w, conv_b, states, cumb, cdec, xtg, bg);
        ssd_scan<<<BATCH * N_QK * 4, 256, 0, stream>>>(states, cdec);
        ssd_out<true><<<dim3(N_QK, NCHUNK, BATCH), 512, 0, stream>>>(
            xbcza, cumb, states, Dv, z_bias, conv_w, conv_b, xtg, bg, yzb);
    } else {
        ssd_states<false><<<dim3(N_QK, NCHUNK, BATCH), 512, 0, stream>>>(
            xbcza, conv_w, conv_b, states, cumb, cdec, nullptr, nullptr);
        ssd_scan<<<BATCH * N_QK * 4, 256, 0, stream>>>(states, cdec);
        ssd_out<false><<<dim3(N_QK, NCHUNK, BATCH), 512, 0, stream>>>(
            xbcza, cumb, states, Dv, z_bias, conv_w, conv_b, nullptr, nullptr, yzb);
    }

    // GEMM2: out = yz @ W_out^T  (8192 x 2048 x 2048), 256 wgs
    gemm256<8, D_INNER, false><<<(M_ROWS / 256) * 8, 512, 0, stream>>>(
        yzb, wob, out, D_MODEL);
}

// Round 16
// 713.099 us; speedup vs baseline: 1.0604x; 1.0248x over previous
//
#include <hip/hip_runtime.h>
#include <math.h>

#define D_MODEL  2048
#define D_INNER  2048
#define N_QK     32
#define N_V      32
#define D_STATE  64
#define D_CONV   4
#define CHUNK    128
#define CONV_DIM 6144      // D_INNER + 2*N_QK*D_STATE
#define IN_OUT   8224      // 2*D_INNER + 2*N_QK*D_STATE + N_V
#define BATCH    2
#define SEQ      4096
#define M_ROWS   (BATCH*SEQ)   // 8192
#define NCHUNK   (SEQ/CHUNK)   // 32

typedef unsigned short bf16_t;
typedef __attribute__((ext_vector_type(4))) float f32x4;
typedef __attribute__((ext_vector_type(8))) short bf16x8;

// swizzled row-major LDS index (elem units); XOR bits 3-5 spread rows over banks
#define SWZ64(r,c)  ((((r)*64)  + (c)) ^ (((r)&7)<<3))
#define SWZ128(r,c) ((((r)*128) + (c)) ^ (((r)&7)<<3))

__device__ __forceinline__ float b2f(bf16_t u) {
    union { unsigned int i; float f; } w; w.i = ((unsigned int)u) << 16; return w.f;
}
__device__ __forceinline__ bf16_t f2b(float f) {
    unsigned int x = __float_as_uint(f);
    return (bf16_t)((x + 0x7FFFu + ((x >> 16) & 1u)) >> 16);   // RNE
}
__device__ __forceinline__ void store4b(bf16_t* dst, float4 v) {
    ushort4 u; u.x = f2b(v.x); u.y = f2b(v.y); u.z = f2b(v.z); u.w = f2b(v.w);
    *reinterpret_cast<ushort4*>(dst) = u;
}

__device__ __forceinline__ void gload_lds16(const bf16_t* g, bf16_t* l) {
    __builtin_amdgcn_global_load_lds((const __attribute__((address_space(1))) void*)g,
                                     (__attribute__((address_space(3))) void*)l,
                                     16, 0, 0);
}

// ---------------------------------------------------------------------------
// fused fp32 -> bf16 convert (grid-stride, 2048 blocks)
// ---------------------------------------------------------------------------
__global__ __launch_bounds__(256) void f2b3_kernel(const float* __restrict__ a0, bf16_t* __restrict__ o0, long n0,
                                                   const float* __restrict__ a1, bf16_t* __restrict__ o1, long n1,
                                                   const float* __restrict__ a2, bf16_t* __restrict__ o2, long n2)
{
    const long total = (n0 + n1 + n2) >> 2;
    for (long s = (long)blockIdx.x * 256 + threadIdx.x; s < total; s += (long)gridDim.x * 256) {
        long i = s << 2;
        const float* in; bf16_t* out;
        if (i < n0)           { in = a0 + i; out = o0 + i; }
        else if (i < n0 + n1) { i -= n0; in = a1 + i; out = o1 + i; }
        else                  { i -= n0 + n1; in = a2 + i; out = o2 + i; }
        float4 v = *reinterpret_cast<const float4*>(in);
        ushort4 o;
        o.x = f2b(v.x); o.y = f2b(v.y); o.z = f2b(v.z); o.w = f2b(v.w);
        *reinterpret_cast<ushort4*>(out) = o;
    }
}

// ---------------------------------------------------------------------------
// 256x256 bf16 MFMA NT-GEMM, K-half counted-vmcnt pipeline, 2 barriers/tile.
// (R12/R13-proven structure -- do not touch.)
// ---------------------------------------------------------------------------
template<int NTB, int K, bool OBF16>
__global__ __launch_bounds__(512, 2) void gemm256(const bf16_t* __restrict__ A,
                                                  const bf16_t* __restrict__ B,
                                                  void* __restrict__ Cv,
                                                  long ldc)
{
    constexpr int BK = 64;
    constexpr int NT = K / BK;
    __shared__ bf16_t As[2][2][8192];   // [buf][kh][1024 slots * 8 elems]
    __shared__ bf16_t Bs[2][2][8192];

    const int nwg = gridDim.x;
    const int bid = blockIdx.x;
    const int wg  = ((nwg & 7) == 0) ? ((bid & 7) * (nwg >> 3) + (bid >> 3)) : bid;
    const int bm = (wg / NTB) * 256;
    const int bn = (wg % NTB) * 256;

    const int tid  = threadIdx.x;
    const int lane = tid & 63;
    const int wv   = tid >> 6;
    const int wr   = wv >> 2, wc = wv & 3;       // 2x4 wave grid
    const int l15  = lane & 15, l4 = lane >> 4;

    f32x4 acc[8][4];
    #pragma unroll
    for (int i = 0; i < 8; ++i)
        #pragma unroll
        for (int j = 0; j < 4; ++j) acc[i][j] = (f32x4){0.f, 0.f, 0.f, 0.f};

    const bf16_t* Abase = A + (long)bm * K;
    const bf16_t* Bbase = B + (long)bn * K;

    auto stage_half = [&](int t, int buf, int kh) {
        #pragma unroll
        for (int it = 0; it < 2; ++it) {
            const int s   = it * 512 + tid;          // 0..1023
            const int row = s >> 2;                  // 0..255
            const int jp  = s & 3;                   // physical chunk in half
            const int jl  = jp ^ ((row >> 1) & 3);   // logical chunk in half
            const long go = (long)row * K + t * BK + kh * 32 + jl * 8;
            gload_lds16(Abase + go, &As[buf][kh][s * 8]);
            gload_lds16(Bbase + go, &Bs[buf][kh][s * 8]);
        }
    };
    auto rdA = [&](int buf, int kh, int row) {
        const int jp = l4 ^ ((row >> 1) & 3);
        return *reinterpret_cast<const bf16x8*>(&As[buf][kh][(row * 4 + jp) * 8]);
    };
    auto rdB = [&](int buf, int kh, int row) {
        const int jp = l4 ^ ((row >> 1) & 3);
        return *reinterpret_cast<const bf16x8*>(&Bs[buf][kh][(row * 4 + jp) * 8]);
    };

    stage_half(0, 0, 0);
    stage_half(0, 0, 1);
    asm volatile("s_waitcnt vmcnt(4)" ::: "memory");   // K-half0 of tile 0 landed
    __builtin_amdgcn_s_barrier();

    for (int t = 0; t < NT; ++t) {
        const int cur = t & 1;
        bf16x8 bfr[4], af[4];
        if (t + 1 < NT) stage_half(t + 1, cur ^ 1, 0);
        // K-half 0: qm=0 then qm=1
        #pragma unroll
        for (int ni = 0; ni < 4; ++ni) bfr[ni] = rdB(cur, 0, wc * 64 + ni * 16 + l15);
        #pragma unroll
        for (int mi = 0; mi < 4; ++mi) af[mi] = rdA(cur, 0, wr * 128 + mi * 16 + l15);
        __builtin_amdgcn_s_setprio(1);
        #pragma unroll
        for (int mi = 0; mi < 4; ++mi)
            #pragma unroll
            for (int ni = 0; ni < 4; ++ni)
                acc[mi][ni] = __builtin_amdgcn_mfma_f32_16x16x32_bf16(
                    af[mi], bfr[ni], acc[mi][ni], 0, 0, 0);
        __builtin_amdgcn_s_setprio(0);
        #pragma unroll
        for (int mi = 0; mi < 4; ++mi) af[mi] = rdA(cur, 0, wr * 128 + 64 + mi * 16 + l15);
        __builtin_amdgcn_s_setprio(1);
        #pragma unroll
        for (int mi = 0; mi < 4; ++mi)
            #pragma unroll
            for (int ni = 0; ni < 4; ++ni)
                acc[4 + mi][ni] = __builtin_amdgcn_mfma_f32_16x16x32_bf16(
                    af[mi], bfr[ni], acc[4 + mi][ni], 0, 0, 0);
        __builtin_amdgcn_s_setprio(0);
        if (t + 1 < NT) {
            stage_half(t + 1, cur ^ 1, 1);
            asm volatile("s_waitcnt vmcnt(8)" ::: "memory");   // K1(t) landed
        } else {
            asm volatile("s_waitcnt vmcnt(0)" ::: "memory");
        }
        __builtin_amdgcn_s_barrier();
        // K-half 1: qm=0 then qm=1
        #pragma unroll
        for (int ni = 0; ni < 4; ++ni) bfr[ni] = rdB(cur, 1, wc * 64 + ni * 16 + l15);
        #pragma unroll
        for (int mi = 0; mi < 4; ++mi) af[mi] = rdA(cur, 1, wr * 128 + mi * 16 + l15);
        __builtin_amdgcn_s_setprio(1);
        #pragma unroll
        for (int mi = 0; mi < 4; ++mi)
            #pragma unroll
            for (int ni = 0; ni < 4; ++ni)
                acc[mi][ni] = __builtin_amdgcn_mfma_f32_16x16x32_bf16(
                    af[mi], bfr[ni], acc[mi][ni], 0, 0, 0);
        __builtin_amdgcn_s_setprio(0);
        #pragma unroll
        for (int mi = 0; mi < 4; ++mi) af[mi] = rdA(cur, 1, wr * 128 + 64 + mi * 16 + l15);
        __builtin_amdgcn_s_setprio(1);
        #pragma unroll
        for (int mi = 0; mi < 4; ++mi)
            #pragma unroll
            for (int ni = 0; ni < 4; ++ni)
                acc[4 + mi][ni] = __builtin_amdgcn_mfma_f32_16x16x32_bf16(
                    af[mi], bfr[ni], acc[4 + mi][ni], 0, 0, 0);
        __builtin_amdgcn_s_setprio(0);
        if (t + 1 < NT) { asm volatile("s_waitcnt vmcnt(4)" ::: "memory"); }
        __builtin_amdgcn_s_barrier();
    }

    #pragma unroll
    for (int mf = 0; mf < 8; ++mf) {
        const long grow0 = bm + wr * 128 + mf * 16 + l4 * 4;
        #pragma unroll
        for (int ni = 0; ni < 4; ++ni) {
            const int gcol = bn + wc * 64 + ni * 16 + l15;
            #pragma unroll
            for (int j = 0; j < 4; ++j) {
                if (OBF16)
                    ((bf16_t*)Cv)[(grow0 + j) * ldc + gcol] = f2b(acc[mf][ni][j]);
                else
                    ((float*)Cv)[(grow0 + j) * ldc + gcol] = acc[mf][ni][j];
            }
        }
    }
}

// ---------------------------------------------------------------------------
// A_log split-K partial GEMM: P[ks][m][h] = sum_{k in slice ks} ub[m][k]*wt[h][k]
// 256 blocks = 64 row-tiles x 4 K-slices; 256 thr = 4 waves, each 32x32 out.
// ---------------------------------------------------------------------------
__global__ __launch_bounds__(256) void alog_partial(const bf16_t* __restrict__ A,
                                                    const bf16_t* __restrict__ Bt,
                                                    float* __restrict__ P)
{
    const int rb = blockIdx.x & 63, ks = blockIdx.x >> 6;
    const int bm = rb * 128;
    __shared__ bf16_t As[128 * 64];   // involution layout (R5-proven)
    __shared__ bf16_t Bs[32 * 64];
    const int tid = threadIdx.x, lane = tid & 63, wv = tid >> 6;
    const int l15 = lane & 15, l4 = lane >> 4;

    f32x4 acc[2][2];
    #pragma unroll
    for (int mi = 0; mi < 2; ++mi)
        #pragma unroll
        for (int nj = 0; nj < 2; ++nj) acc[mi][nj] = (f32x4){0.f, 0.f, 0.f, 0.f};

    for (int it8 = 0; it8 < 8; ++it8) {
        const long kbase = (long)ks * 512 + it8 * 64;
        #pragma unroll
        for (int it = 0; it < 4; ++it) {
            const int s = it * 256 + tid;            // 1024 slots
            const int row = s >> 3, c16 = s & 7;
            gload_lds16(A + (long)(bm + row) * D_MODEL + kbase + (c16 ^ (row & 7)) * 8,
                        &As[s * 8]);
        }
        {
            const int row = tid >> 3, c16 = tid & 7;  // 256 slots
            gload_lds16(Bt + (long)row * D_MODEL + kbase + (c16 ^ (row & 7)) * 8,
                        &Bs[tid * 8]);
        }
        __syncthreads();
        #pragma unroll
        for (int kk = 0; kk < 2; ++kk) {
            bf16x8 bf[2], af;
            #pragma unroll
            for (int nj = 0; nj < 2; ++nj) {
                const int row = nj * 16 + l15;
                bf[nj] = *reinterpret_cast<const bf16x8*>(&Bs[row * 64 + (((kk * 4 + l4) ^ (row & 7)) << 3)]);
            }
            #pragma unroll
            for (int mi = 0; mi < 2; ++mi) {
                const int row = wv * 32 + mi * 16 + l15;
                af = *reinterpret_cast<const bf16x8*>(&As[row * 64 + (((kk * 4 + l4) ^ (row & 7)) << 3)]);
                #pragma unroll
                for (int nj = 0; nj < 2; ++nj)
                    acc[mi][nj] = __builtin_amdgcn_mfma_f32_16x16x32_bf16(af, bf[nj], acc[mi][nj], 0, 0, 0);
            }
        }
        __syncthreads();
    }
    #pragma unroll
    for (int mi = 0; mi < 2; ++mi)
        #pragma unroll
        for (int nj = 0; nj < 2; ++nj)
            #pragma unroll
            for (int j = 0; j < 4; ++j) {
                const int row = bm + wv * 32 + mi * 16 + l4 * 4 + j;
                P[(long)ks * (M_ROWS * 32) + (long)row * 32 + nj * 16 + l15] = acc[mi][nj][j];
            }
}

// dt = softplus(sum of 4 K-slice partials)
__global__ __launch_bounds__(256) void alog_fin(const float* __restrict__ P,
                                                float* __restrict__ dt)
{
    const long i = (long)blockIdx.x * 256 + threadIdx.x;
    if (i < (long)M_ROWS * 32) {
        const long n = (long)M_ROWS * 32;
        const float a = P[i] + P[n + i] + P[2 * n + i] + P[3 * n + i];
        dt[i] = (a > 20.f) ? a : log1pf(expf(a));
    }
}

// ---------------------------------------------------------------------------
// Fused causal depthwise conv (K=4), 4 consecutive columns, reading bf16 xBCzA.
// ---------------------------------------------------------------------------
__device__ __forceinline__ float4 conv4v(const bf16_t* __restrict__ xb, long m, int l,
                                         int col, const float* __restrict__ cw,
                                         const float* __restrict__ cbv)
{
    float4 acc = *reinterpret_cast<const float4*>(cbv + col);
    float4 wc0 = *reinterpret_cast<const float4*>(cw + (long)col * 4);
    float4 wc1 = *reinterpret_cast<const float4*>(cw + (long)col * 4 + 4);
    float4 wc2 = *reinterpret_cast<const float4*>(cw + (long)col * 4 + 8);
    float4 wc3 = *reinterpret_cast<const float4*>(cw + (long)col * 4 + 12);
    const float t0[4] = {wc0.x, wc0.y, wc0.z, wc0.w};
    const float t1[4] = {wc1.x, wc1.y, wc1.z, wc1.w};
    const float t2[4] = {wc2.x, wc2.y, wc2.z, wc2.w};
    const float t3[4] = {wc3.x, wc3.y, wc3.z, wc3.w};
    #pragma unroll
    for (int tap = 0; tap < 4; ++tap) {
        if (l - 3 + tap < 0) continue;
        const bf16_t* p = xb + (m - 3 + tap) * (long)IN_OUT + col;
        ushort4 v = *reinterpret_cast<const ushort4*>(p);
        acc.x = fmaf(b2f(v.x), t0[tap], acc.x);
        acc.y = fmaf(b2f(v.y), t1[tap], acc.y);
        acc.z = fmaf(b2f(v.z), t2[tap], acc.z);
        acc.w = fmaf(b2f(v.w), t3[tap], acc.w);
    }
    return acc;
}

// ---------------------------------------------------------------------------
// Phase A (MFMA): 512 threads / 8 waves; dt read from dtb (precomputed).
// ---------------------------------------------------------------------------
template<bool EXP>
__global__ __launch_bounds__(512, 4) void ssd_states(const bf16_t* __restrict__ xb,
                                                     const float* __restrict__ dtb,
                                                     const float* __restrict__ cw,
                                                     const float* __restrict__ cbv,
                                                     bf16_t* __restrict__ states,
                                                     float* __restrict__ cumbuf,
                                                     float* __restrict__ cdecay,
                                                     bf16_t* __restrict__ xtg,
                                                     bf16_t* __restrict__ bg)
{
    const int h = blockIdx.x, c = blockIdx.y, b = blockIdx.z;
    __shared__ bf16_t sx [128 * 64];
    __shared__ bf16_t sBr[128 * 64];
    __shared__ bf16_t sXT[64 * 128];
    __shared__ bf16_t sBT[64 * 128];
    __shared__ float  cum[CHUNK];
    __shared__ float  w0tot;
    const int t = threadIdx.x;
    const long mbase = (long)b * SEQ + (long)c * CHUNK;
    const long cb = ((long)b * NCHUNK + c) * N_QK + h;

    float v = 0.f;
    if (t < CHUNK) {
        v = -dtb[(mbase + t) * N_V + h];
        #pragma unroll
        for (int s = 1; s < 64; s <<= 1) {
            const float u2 = __shfl_up(v, s, 64);
            if ((t & 63) >= s) v += u2;
        }
        if (t == 63) w0tot = v;
    }
    for (int idx = t; idx < CHUNK * 16; idx += 512) {
        const int k = idx >> 4, q4 = (idx & 15) * 4;
        const long m = mbase + k;
        const int l = (int)(m & (SEQ - 1));
        float4 xv = conv4v(xb, m, l, h * 64 + q4, cw, cbv);
        float4 bv = conv4v(xb, m, l, D_INNER + h * 64 + q4, cw, cbv);
        store4b(&sx [SWZ64(k, q4)], xv);
        store4b(&sBr[SWZ64(k, q4)], bv);
    }
    __syncthreads();
    if (t >= 64 && t < CHUNK) v += w0tot;
    if (t < CHUNK) cum[t] = v;
    __syncthreads();
    const float clast = cum[CHUNK - 1];
    {
        const int j = t & 127;
        const int c8b = (t >> 7) * 2;
        const float ej = __expf(clast - cum[j]);
        #pragma unroll
        for (int it = 0; it < 2; ++it) {
            const int c8 = c8b + it;
            bf16x8 xv = *reinterpret_cast<const bf16x8*>(&sx [SWZ64(j, c8 * 8)]);
            bf16x8 bv = *reinterpret_cast<const bf16x8*>(&sBr[SWZ64(j, c8 * 8)]);
            #pragma unroll
            for (int e = 0; e < 8; ++e) {
                sXT[SWZ128(c8 * 8 + e, j)] = xv[e];
                sBT[SWZ128(c8 * 8 + e, j)] = f2b(b2f((bf16_t)bv[e]) * ej);
            }
        }
    }
    __syncthreads();

    const int lane = t & 63, wv = t >> 6;       // wv 0..7
    const int l15 = lane & 15, l4 = lane >> 4;
    const int prow  = (wv & 3) * 16;
    const int nbase = (wv >> 2) * 2;
    f32x4 acc[2];
    acc[0] = (f32x4){0.f, 0.f, 0.f, 0.f};
    acc[1] = (f32x4){0.f, 0.f, 0.f, 0.f};
    #pragma unroll
    for (int ks = 0; ks < 4; ++ks) {
        const int kc = ks * 32 + l4 * 8;
        bf16x8 af = *reinterpret_cast<const bf16x8*>(&sXT[SWZ128(prow + l15, kc)]);
        #pragma unroll
        for (int nj = 0; nj < 2; ++nj) {
            bf16x8 bf = *reinterpret_cast<const bf16x8*>(&sBT[SWZ128((nbase + nj) * 16 + l15, kc)]);
            acc[nj] = __builtin_amdgcn_mfma_f32_16x16x32_bf16(af, bf, acc[nj], 0, 0, 0);
        }
    }
    #pragma unroll
    for (int nj = 0; nj < 2; ++nj) {
        #pragma unroll
        for (int jj = 0; jj < 4; ++jj) {
            const int p = prow + l4 * 4 + jj;
            states[cb * 4096 + SWZ64(p, (nbase + nj) * 16 + l15)] = f2b(acc[nj][jj]);
        }
    }
    if constexpr (EXP) {
        #pragma unroll
        for (int it = 0; it < 2; ++it) {
            const int s = it * 512 + t;
            *reinterpret_cast<bf16x8*>(xtg + cb * 8192 + s * 8) =
                *reinterpret_cast<const bf16x8*>(&sXT[s * 8]);
            *reinterpret_cast<bf16x8*>(bg + cb * 8192 + s * 8) =
                *reinterpret_cast<const bf16x8*>(&sBr[s * 8]);
        }
    }
    if (t < CHUNK) cumbuf[cb * CHUNK + t] = cum[t];
    if (t == 0)   cdecay[cb] = __expf(clast);
}

// ---------------------------------------------------------------------------
// Phase B: inter-chunk scan, LDS-staged, 8 slices per (b,h) (512 blocks).
// ---------------------------------------------------------------------------
__global__ __launch_bounds__(256) void ssd_scan(bf16_t* __restrict__ states,
                                                const float* __restrict__ cdecay)
{
    const int bid = blockIdx.x;
    const int bh = bid >> 3, q = bid & 7;
    const int b = bh >> 5, h = bh & 31;
    const int t = threadIdx.x;
    __shared__ bf16_t sst[NCHUNK * 512];   // 32 KiB
    __shared__ float  scd[NCHUNK];
    if (t < NCHUNK) scd[t] = cdecay[((long)b * NCHUNK + t) * N_QK + h];
    #pragma unroll
    for (int it = 0; it < 8; ++it) {
        const int slot = it * 256 + t;          // 2048 slots x 16B
        const int c = slot >> 6, off = (slot & 63) * 8;
        const long g = (((long)b * NCHUNK + c) * N_QK + h) * 4096 + q * 512 + off;
        gload_lds16(states + g, &sst[slot * 8]);
    }
    __syncthreads();
    float2 carry = make_float2(0.f, 0.f);
    for (int c = 0; c < NCHUNK; ++c) {
        ushort2* p = reinterpret_cast<ushort2*>(&sst[c * 512 + t * 2]);
        const ushort2 su = *p;
        ushort2 pv;
        pv.x = f2b(carry.x); pv.y = f2b(carry.y);
        *p = pv;
        const float cd = scd[c];
        carry.x = fmaf(carry.x, cd, b2f(su.x));
        carry.y = fmaf(carry.y, cd, b2f(su.y));
    }
    __syncthreads();
    #pragma unroll
    for (int it = 0; it < 8; ++it) {
        const int slot = it * 256 + t;
        const int c = slot >> 6, off = (slot & 63) * 8;
        const long g = (((long)b * NCHUNK + c) * N_QK + h) * 4096 + q * 512 + off;
        *reinterpret_cast<bf16x8*>(states + g) =
            *reinterpret_cast<const bf16x8*>(&sst[slot * 8]);
    }
}

// ---------------------------------------------------------------------------
// Phase C (MFMA): 512 threads / 8 waves, each owning 16 output rows.
// ---------------------------------------------------------------------------
template<bool EXP>
__global__ __launch_bounds__(512, 4) void ssd_out(const bf16_t* __restrict__ xb,
                                                  const float* __restrict__ cumbuf,
                                                  const bf16_t* __restrict__ prevst,
                                                  const float* __restrict__ Dvec,
                                                  const float* __restrict__ zbias,
                                                  const float* __restrict__ cw,
                                                  const float* __restrict__ cbv,
                                                  const bf16_t* __restrict__ xtg,
                                                  const bf16_t* __restrict__ bg,
                                                  bf16_t* __restrict__ yz)
{
    const int h = blockIdx.x, c = blockIdx.y, b = blockIdx.z;
    __shared__ bf16_t sC[128 * 64];
    __shared__ bf16_t sB[128 * 64];
    __shared__ bf16_t sXQ[128 * 64];   // x tile (FB) / Q scratch
    __shared__ bf16_t sXT[64 * 128];   // x^T
    __shared__ bf16_t sP[64 * 64];     // prev state (bf16, SWZ64-physical)
    __shared__ float  cum[CHUNK];
    const int t = threadIdx.x;
    const long mbase = (long)b * SEQ + (long)c * CHUNK;
    const long cb = ((long)b * NCHUNK + c) * N_QK + h;
    if (t < CHUNK) cum[t] = cumbuf[cb * CHUNK + t];
    gload_lds16(prevst + cb * 4096 + t * 8, &sP[t * 8]);
    if constexpr (EXP) {
        #pragma unroll
        for (int it = 0; it < 2; ++it) {
            const int s = it * 512 + t;
            gload_lds16(bg  + cb * 8192 + s * 8, &sB [s * 8]);
            gload_lds16(xtg + cb * 8192 + s * 8, &sXT[s * 8]);
        }
        for (int idx = t; idx < CHUNK * 16; idx += 512) {
            const int k = idx >> 4, q4 = (idx & 15) * 4;
            const long m = mbase + k;
            const int l = (int)(m & (SEQ - 1));
            float4 cv = conv4v(xb, m, l, 2 * D_INNER + h * 64 + q4, cw, cbv);
            store4b(&sC[SWZ64(k, q4)], cv);
        }
        __syncthreads();
    } else {
        for (int idx = t; idx < CHUNK * 16; idx += 512) {
            const int k = idx >> 4, q4 = (idx & 15) * 4;
            const long m = mbase + k;
            const int l = (int)(m & (SEQ - 1));
            float4 xv = conv4v(xb, m, l, h * 64 + q4, cw, cbv);
            float4 bv = conv4v(xb, m, l, D_INNER + h * 64 + q4, cw, cbv);
            float4 cv = conv4v(xb, m, l, 2 * D_INNER + h * 64 + q4, cw, cbv);
            store4b(&sXQ[SWZ64(k, q4)], xv);
            store4b(&sB [SWZ64(k, q4)], bv);
            store4b(&sC [SWZ64(k, q4)], cv);
        }
        __syncthreads();
        {
            const int j = t & 127;
            const int c8b = (t >> 7) * 2;
            #pragma unroll
            for (int it = 0; it < 2; ++it) {
                const int c8 = c8b + it;
                bf16x8 v = *reinterpret_cast<const bf16x8*>(&sXQ[SWZ64(j, c8 * 8)]);
                #pragma unroll
                for (int e = 0; e < 8; ++e) sXT[SWZ128(c8 * 8 + e, j)] = v[e];
            }
        }
        __syncthreads();
    }

    const int lane = t & 63, wv = t >> 6;       // wv 0..7
    const int w16 = wv * 16, l15 = lane & 15, l4 = lane >> 4;
    bf16_t* sQ = sXQ;

    f32x4 yac[4], iac[4];
    #pragma unroll
    for (int np = 0; np < 4; ++np) {
        yac[np] = (f32x4){0.f, 0.f, 0.f, 0.f};
        iac[np] = (f32x4){0.f, 0.f, 0.f, 0.f};
    }

    #pragma unroll
    for (int H = 0; H < 2; ++H) {
        if (H == 1 && wv < 4) break;
        const int j0 = H * 64;
        f32x4 sac[4];
        #pragma unroll
        for (int nj = 0; nj < 4; ++nj) sac[nj] = (f32x4){0.f, 0.f, 0.f, 0.f};
        #pragma unroll
        for (int kk = 0; kk < 2; ++kk) {
            const int kc = kk * 32 + l4 * 8;
            bf16x8 af0 = *reinterpret_cast<const bf16x8*>(&sC[SWZ64(w16 + l15, kc)]);
            #pragma unroll
            for (int nj = 0; nj < 4; ++nj) {
                if (j0 + nj * 16 <= w16 + 15) {
                    bf16x8 bfj = *reinterpret_cast<const bf16x8*>(&sB[SWZ64(j0 + nj * 16 + l15, kc)]);
                    sac[nj] = __builtin_amdgcn_mfma_f32_16x16x32_bf16(af0, bfj, sac[nj], 0, 0, 0);
                }
            }
        }
        #pragma unroll
        for (int nj = 0; nj < 4; ++nj) {
            const int jcol = nj * 16 + l15;
            const int jg = j0 + jcol;
            #pragma unroll
            for (int jj = 0; jj < 4; ++jj) {
                const int i = w16 + l4 * 4 + jj;
                const float q = (jg <= i) ? __expf(cum[i] - cum[jg]) * sac[nj][jj] : 0.f;
                sQ[SWZ64(i, jcol)] = f2b(q);
            }
        }
        #pragma unroll
        for (int kk = 0; kk < 2; ++kk) {
            const int kc = kk * 32 + l4 * 8;
            bf16x8 qa = *reinterpret_cast<const bf16x8*>(&sQ[SWZ64(w16 + l15, kc)]);
            #pragma unroll
            for (int np = 0; np < 4; ++np) {
                bf16x8 xf = *reinterpret_cast<const bf16x8*>(&sXT[SWZ128(np * 16 + l15, j0 + kc)]);
                yac[np] = __builtin_amdgcn_mfma_f32_16x16x32_bf16(qa, xf, yac[np], 0, 0, 0);
            }
        }
    }
    #pragma unroll
    for (int kk = 0; kk < 2; ++kk) {
        const int kc = kk * 32 + l4 * 8;
        bf16x8 cf = *reinterpret_cast<const bf16x8*>(&sC[SWZ64(w16 + l15, kc)]);
        #pragma unroll
        for (int np = 0; np < 4; ++np) {
            bf16x8 pf = *reinterpret_cast<const bf16x8*>(&sP[SWZ64(np * 16 + l15, kc)]);
            iac[np] = __builtin_amdgcn_mfma_f32_16x16x32_bf16(cf, pf, iac[np], 0, 0, 0);
        }
    }
    const float dh = Dvec[h];
    #pragma unroll
    for (int jj = 0; jj < 4; ++jj) {
        const int i = w16 + l4 * 4 + jj;
        const float ei = __expf(cum[i]);
        const long m = mbase + i;
        const bf16_t* zr = xb + m * (long)IN_OUT + CONV_DIM + h * 64;
        bf16_t* orow = yz + m * (long)D_INNER + h * 64;
        #pragma unroll
        for (int np = 0; np < 4; ++np) {
            const int p = np * 16 + l15;
            const float xval = b2f(sXT[SWZ128(p, i)]);
            const float y = yac[np][jj] + ei * iac[np][jj] + dh * xval;
            const float zv = b2f(zr[p]) + zbias[h * 64 + p];
            const float s = zv / (1.f + __expf(-zv));
            orow[p] = f2b(y * s);
        }
    }
}

// ---------------------------------------------------------------------------
extern "C" void kernel_launch(void* const* d_in, const int* in_sizes, int n_in,
                              void* d_out, int out_size, void* d_ws, size_t ws_size,
                              hipStream_t stream)
{
    const float* u      = (const float*)d_in[0];
    const float* W_in   = (const float*)d_in[1];
    const float* conv_w = (const float*)d_in[2];
    const float* conv_b = (const float*)d_in[3];
    const float* Dv     = (const float*)d_in[4];
    const float* z_bias = (const float*)d_in[5];
    const float* W_out  = (const float*)d_in[6];
    float* out = (float*)d_out;

    char* w = (char*)d_ws;
    bf16_t* xbcza = (bf16_t*)w;  w += (long)M_ROWS * IN_OUT * 2;   // 128.5 MiB
    bf16_t* wob   = (bf16_t*)w;  w += (long)2048 * 2048 * 2;       //   8 MiB
    char* ureg = w;  w += 67239936;                                 // 64.1 MiB union
    bf16_t* ub  = (bf16_t*)ureg;                                    // 32 MiB (phase 1)
    bf16_t* wib = (bf16_t*)(ureg + (long)M_ROWS * D_MODEL * 2);     // 32.125 MiB (phase 1)
    bf16_t* yzb = (bf16_t*)ureg;                                    // 32 MiB (phase 2)
    float*  cumb   = (float*)(ureg + (long)M_ROWS * D_INNER * 2);   //  1 MiB
    bf16_t* states = (bf16_t*)(cumb + (long)BATCH * NCHUNK * N_QK * CHUNK); // 16 MiB
    float*  cdec   = (float*)(states + (long)BATCH * NCHUNK * N_QK * 4096); //  8 KiB
    // A_log split-K scratch, placed in wib's dead middle rows (4096..5376):
    //   partials @ ureg+48MiB (4 MiB), dtb @ ureg+52MiB (1 MiB). Both written
    //   after gemm1 (wib rows <8192 dead); partials die before states overwrite.
    float* partials = (float*)(ureg + 50331648);
    float* dtb      = (float*)(ureg + 54525952);
    const long base_bytes = (long)(w - (char*)d_ws);
    const long exp_bytes  = 2L * 2048 * 8192 * 2;                   // xtg + bg
    const bool use_exp = ((long)ws_size >= base_bytes + exp_bytes);
    bf16_t* xtg = (bf16_t*)w;
    bf16_t* bg  = xtg + (long)2048 * 8192;

    // fused fp32->bf16 conversions (u, W_in, W_out), grid-stride
    {
        const long n0 = (long)M_ROWS * D_MODEL;
        const long n1 = (long)IN_OUT * D_MODEL;
        const long n2 = (long)D_MODEL * D_INNER;
        f2b3_kernel<<<2048, 256, 0, stream>>>(u, ub, n0, W_in, wib, n1, W_out, wob, n2);
    }

    // GEMM1 main: cols [0, 8192), 1024 wgs, bm-major
    gemm256<32, D_MODEL, true><<<(M_ROWS / 256) * 32, 512, 0, stream>>>(
        ub, wib, xbcza, IN_OUT);

    // A_log tail -> dt, split-K (256 blocks) + reduce/softplus
    alog_partial<<<256, 256, 0, stream>>>(ub, wib + (long)8192 * D_MODEL, partials);
    alog_fin<<<(M_ROWS * 32 + 255) / 256, 256, 0, stream>>>(partials, dtb);

    if (use_exp) {
        ssd_states<true><<<dim3(N_QK, NCHUNK, BATCH), 512, 0, stream>>>(
            xbcza, dtb, conv_w, conv_b, states, cumb, cdec, xtg, bg);
        ssd_scan<<<BATCH * N_QK * 8, 256, 0, stream>>>(states, cdec);
        ssd_out<true><<<dim3(N_QK, NCHUNK, BATCH), 512, 0, stream>>>(
            xbcza, cumb, states, Dv, z_bias, conv_w, conv_b, xtg, bg, yzb);
    } else {
        ssd_states<false><<<dim3(N_QK, NCHUNK, BATCH), 512, 0, stream>>>(
            xbcza, dtb, conv_w, conv_b, states, cumb, cdec, nullptr, nullptr);
        ssd_scan<<<BATCH * N_QK * 8, 256, 0, stream>>>(states, cdec);
        ssd_out<false><<<dim3(N_QK, NCHUNK, BATCH), 512, 0, stream>>>(
            xbcza, cumb, states, Dv, z_bias, conv_w, conv_b, nullptr, nullptr, yzb);
    }

    // GEMM2: out = yz @ W_out^T  (8192 x 2048 x 2048), 256 wgs
    gemm256<8, D_INNER, false><<<(M_ROWS / 256) * 8, 512, 0, stream>>>(
        yzb, wob, out, D_MODEL);
}

// Round 17
// 709.247 us; speedup vs baseline: 1.0661x; 1.0054x over previous
//
#include <hip/hip_runtime.h>
#include <math.h>

#define D_MODEL  2048
#define D_INNER  2048
#define N_QK     32
#define N_V      32
#define D_STATE  64
#define D_CONV   4
#define CHUNK    128
#define CONV_DIM 6144      // D_INNER + 2*N_QK*D_STATE
#define IN_OUT   8224      // 2*D_INNER + 2*N_QK*D_STATE + N_V
#define BATCH    2
#define SEQ      4096
#define M_ROWS   (BATCH*SEQ)   // 8192
#define NCHUNK   (SEQ/CHUNK)   // 32

typedef unsigned short bf16_t;
typedef __attribute__((ext_vector_type(4))) float f32x4;
typedef __attribute__((ext_vector_type(8))) short bf16x8;

// swizzled row-major LDS index (elem units); XOR bits 3-5 spread rows over banks
#define SWZ64(r,c)  ((((r)*64)  + (c)) ^ (((r)&7)<<3))
#define SWZ128(r,c) ((((r)*128) + (c)) ^ (((r)&7)<<3))

__device__ __forceinline__ float b2f(bf16_t u) {
    union { unsigned int i; float f; } w; w.i = ((unsigned int)u) << 16; return w.f;
}
__device__ __forceinline__ bf16_t f2b(float f) {
    unsigned int x = __float_as_uint(f);
    return (bf16_t)((x + 0x7FFFu + ((x >> 16) & 1u)) >> 16);   // RNE
}
__device__ __forceinline__ void store4b(bf16_t* dst, float4 v) {
    ushort4 u; u.x = f2b(v.x); u.y = f2b(v.y); u.z = f2b(v.z); u.w = f2b(v.w);
    *reinterpret_cast<ushort4*>(dst) = u;
}

__device__ __forceinline__ void gload_lds16(const bf16_t* g, bf16_t* l) {
    __builtin_amdgcn_global_load_lds((const __attribute__((address_space(1))) void*)g,
                                     (__attribute__((address_space(3))) void*)l,
                                     16, 0, 0);
}

// ---------------------------------------------------------------------------
// fused fp32 -> bf16 convert (grid-stride, 2048 blocks)
// ---------------------------------------------------------------------------
__global__ __launch_bounds__(256) void f2b3_kernel(const float* __restrict__ a0, bf16_t* __restrict__ o0, long n0,
                                                   const float* __restrict__ a1, bf16_t* __restrict__ o1, long n1,
                                                   const float* __restrict__ a2, bf16_t* __restrict__ o2, long n2)
{
    const long total = (n0 + n1 + n2) >> 2;
    for (long s = (long)blockIdx.x * 256 + threadIdx.x; s < total; s += (long)gridDim.x * 256) {
        long i = s << 2;
        const float* in; bf16_t* out;
        if (i < n0)           { in = a0 + i; out = o0 + i; }
        else if (i < n0 + n1) { i -= n0; in = a1 + i; out = o1 + i; }
        else                  { i -= n0 + n1; in = a2 + i; out = o2 + i; }
        float4 v = *reinterpret_cast<const float4*>(in);
        ushort4 o;
        o.x = f2b(v.x); o.y = f2b(v.y); o.z = f2b(v.z); o.w = f2b(v.w);
        *reinterpret_cast<ushort4*>(out) = o;
    }
}

// ---------------------------------------------------------------------------
// 256x256 bf16 MFMA NT-GEMM, K-half counted-vmcnt pipeline, 2 barriers/tile.
// (R12/R13-proven structure -- do not touch.)
// ---------------------------------------------------------------------------
template<int NTB, int K, bool OBF16>
__global__ __launch_bounds__(512, 2) void gemm256(const bf16_t* __restrict__ A,
                                                  const bf16_t* __restrict__ B,
                                                  void* __restrict__ Cv,
                                                  long ldc)
{
    constexpr int BK = 64;
    constexpr int NT = K / BK;
    __shared__ bf16_t As[2][2][8192];   // [buf][kh][1024 slots * 8 elems]
    __shared__ bf16_t Bs[2][2][8192];

    const int nwg = gridDim.x;
    const int bid = blockIdx.x;
    const int wg  = ((nwg & 7) == 0) ? ((bid & 7) * (nwg >> 3) + (bid >> 3)) : bid;
    const int bm = (wg / NTB) * 256;
    const int bn = (wg % NTB) * 256;

    const int tid  = threadIdx.x;
    const int lane = tid & 63;
    const int wv   = tid >> 6;
    const int wr   = wv >> 2, wc = wv & 3;       // 2x4 wave grid
    const int l15  = lane & 15, l4 = lane >> 4;

    f32x4 acc[8][4];
    #pragma unroll
    for (int i = 0; i < 8; ++i)
        #pragma unroll
        for (int j = 0; j < 4; ++j) acc[i][j] = (f32x4){0.f, 0.f, 0.f, 0.f};

    const bf16_t* Abase = A + (long)bm * K;
    const bf16_t* Bbase = B + (long)bn * K;

    auto stage_half = [&](int t, int buf, int kh) {
        #pragma unroll
        for (int it = 0; it < 2; ++it) {
            const int s   = it * 512 + tid;          // 0..1023
            const int row = s >> 2;                  // 0..255
            const int jp  = s & 3;                   // physical chunk in half
            const int jl  = jp ^ ((row >> 1) & 3);   // logical chunk in half
            const long go = (long)row * K + t * BK + kh * 32 + jl * 8;
            gload_lds16(Abase + go, &As[buf][kh][s * 8]);
            gload_lds16(Bbase + go, &Bs[buf][kh][s * 8]);
        }
    };
    auto rdA = [&](int buf, int kh, int row) {
        const int jp = l4 ^ ((row >> 1) & 3);
        return *reinterpret_cast<const bf16x8*>(&As[buf][kh][(row * 4 + jp) * 8]);
    };
    auto rdB = [&](int buf, int kh, int row) {
        const int jp = l4 ^ ((row >> 1) & 3);
        return *reinterpret_cast<const bf16x8*>(&Bs[buf][kh][(row * 4 + jp) * 8]);
    };

    stage_half(0, 0, 0);
    stage_half(0, 0, 1);
    asm volatile("s_waitcnt vmcnt(4)" ::: "memory");   // K-half0 of tile 0 landed
    __builtin_amdgcn_s_barrier();

    for (int t = 0; t < NT; ++t) {
        const int cur = t & 1;
        bf16x8 bfr[4], af[4];
        if (t + 1 < NT) stage_half(t + 1, cur ^ 1, 0);
        // K-half 0: qm=0 then qm=1
        #pragma unroll
        for (int ni = 0; ni < 4; ++ni) bfr[ni] = rdB(cur, 0, wc * 64 + ni * 16 + l15);
        #pragma unroll
        for (int mi = 0; mi < 4; ++mi) af[mi] = rdA(cur, 0, wr * 128 + mi * 16 + l15);
        __builtin_amdgcn_s_setprio(1);
        #pragma unroll
        for (int mi = 0; mi < 4; ++mi)
            #pragma unroll
            for (int ni = 0; ni < 4; ++ni)
                acc[mi][ni] = __builtin_amdgcn_mfma_f32_16x16x32_bf16(
                    af[mi], bfr[ni], acc[mi][ni], 0, 0, 0);
        __builtin_amdgcn_s_setprio(0);
        #pragma unroll
        for (int mi = 0; mi < 4; ++mi) af[mi] = rdA(cur, 0, wr * 128 + 64 + mi * 16 + l15);
        __builtin_amdgcn_s_setprio(1);
        #pragma unroll
        for (int mi = 0; mi < 4; ++mi)
            #pragma unroll
            for (int ni = 0; ni < 4; ++ni)
                acc[4 + mi][ni] = __builtin_amdgcn_mfma_f32_16x16x32_bf16(
                    af[mi], bfr[ni], acc[4 + mi][ni], 0, 0, 0);
        __builtin_amdgcn_s_setprio(0);
        if (t + 1 < NT) {
            stage_half(t + 1, cur ^ 1, 1);
            asm volatile("s_waitcnt vmcnt(8)" ::: "memory");   // K1(t) landed
        } else {
            asm volatile("s_waitcnt vmcnt(0)" ::: "memory");
        }
        __builtin_amdgcn_s_barrier();
        // K-half 1: qm=0 then qm=1
        #pragma unroll
        for (int ni = 0; ni < 4; ++ni) bfr[ni] = rdB(cur, 1, wc * 64 + ni * 16 + l15);
        #pragma unroll
        for (int mi = 0; mi < 4; ++mi) af[mi] = rdA(cur, 1, wr * 128 + mi * 16 + l15);
        __builtin_amdgcn_s_setprio(1);
        #pragma unroll
        for (int mi = 0; mi < 4; ++mi)
            #pragma unroll
            for (int ni = 0; ni < 4; ++ni)
                acc[mi][ni] = __builtin_amdgcn_mfma_f32_16x16x32_bf16(
                    af[mi], bfr[ni], acc[mi][ni], 0, 0, 0);
        __builtin_amdgcn_s_setprio(0);
        #pragma unroll
        for (int mi = 0; mi < 4; ++mi) af[mi] = rdA(cur, 1, wr * 128 + 64 + mi * 16 + l15);
        __builtin_amdgcn_s_setprio(1);
        #pragma unroll
        for (int mi = 0; mi < 4; ++mi)
            #pragma unroll
            for (int ni = 0; ni < 4; ++ni)
                acc[4 + mi][ni] = __builtin_amdgcn_mfma_f32_16x16x32_bf16(
                    af[mi], bfr[ni], acc[4 + mi][ni], 0, 0, 0);
        __builtin_amdgcn_s_setprio(0);
        if (t + 1 < NT) { asm volatile("s_waitcnt vmcnt(4)" ::: "memory"); }
        __builtin_amdgcn_s_barrier();
    }

    #pragma unroll
    for (int mf = 0; mf < 8; ++mf) {
        const long grow0 = bm + wr * 128 + mf * 16 + l4 * 4;
        #pragma unroll
        for (int ni = 0; ni < 4; ++ni) {
            const int gcol = bn + wc * 64 + ni * 16 + l15;
            #pragma unroll
            for (int j = 0; j < 4; ++j) {
                if (OBF16)
                    ((bf16_t*)Cv)[(grow0 + j) * ldc + gcol] = f2b(acc[mf][ni][j]);
                else
                    ((float*)Cv)[(grow0 + j) * ldc + gcol] = acc[mf][ni][j];
            }
        }
    }
}

// ---------------------------------------------------------------------------
// A_log split-K partial GEMM: P[ks][m][h] = sum_{k in slice ks} ub[m][k]*wt[h][k]
// 256 blocks = 64 row-tiles x 4 K-slices; 256 thr = 4 waves, each 32x32 out.
// ---------------------------------------------------------------------------
__global__ __launch_bounds__(256) void alog_partial(const bf16_t* __restrict__ A,
                                                    const bf16_t* __restrict__ Bt,
                                                    float* __restrict__ P)
{
    const int rb = blockIdx.x & 63, ks = blockIdx.x >> 6;
    const int bm = rb * 128;
    __shared__ bf16_t As[128 * 64];   // involution layout (R5-proven)
    __shared__ bf16_t Bs[32 * 64];
    const int tid = threadIdx.x, lane = tid & 63, wv = tid >> 6;
    const int l15 = lane & 15, l4 = lane >> 4;

    f32x4 acc[2][2];
    #pragma unroll
    for (int mi = 0; mi < 2; ++mi)
        #pragma unroll
        for (int nj = 0; nj < 2; ++nj) acc[mi][nj] = (f32x4){0.f, 0.f, 0.f, 0.f};

    for (int it8 = 0; it8 < 8; ++it8) {
        const long kbase = (long)ks * 512 + it8 * 64;
        #pragma unroll
        for (int it = 0; it < 4; ++it) {
            const int s = it * 256 + tid;            // 1024 slots
            const int row = s >> 3, c16 = s & 7;
            gload_lds16(A + (long)(bm + row) * D_MODEL + kbase + (c16 ^ (row & 7)) * 8,
                        &As[s * 8]);
        }
        {
            const int row = tid >> 3, c16 = tid & 7;  // 256 slots
            gload_lds16(Bt + (long)row * D_MODEL + kbase + (c16 ^ (row & 7)) * 8,
                        &Bs[tid * 8]);
        }
        __syncthreads();
        #pragma unroll
        for (int kk = 0; kk < 2; ++kk) {
            bf16x8 bf[2], af;
            #pragma unroll
            for (int nj = 0; nj < 2; ++nj) {
                const int row = nj * 16 + l15;
                bf[nj] = *reinterpret_cast<const bf16x8*>(&Bs[row * 64 + (((kk * 4 + l4) ^ (row & 7)) << 3)]);
            }
            #pragma unroll
            for (int mi = 0; mi < 2; ++mi) {
                const int row = wv * 32 + mi * 16 + l15;
                af = *reinterpret_cast<const bf16x8*>(&As[row * 64 + (((kk * 4 + l4) ^ (row & 7)) << 3)]);
                #pragma unroll
                for (int nj = 0; nj < 2; ++nj)
                    acc[mi][nj] = __builtin_amdgcn_mfma_f32_16x16x32_bf16(af, bf[nj], acc[mi][nj], 0, 0, 0);
            }
        }
        __syncthreads();
    }
    #pragma unroll
    for (int mi = 0; mi < 2; ++mi)
        #pragma unroll
        for (int nj = 0; nj < 2; ++nj)
            #pragma unroll
            for (int j = 0; j < 4; ++j) {
                const int row = bm + wv * 32 + mi * 16 + l4 * 4 + j;
                P[(long)ks * (M_ROWS * 32) + (long)row * 32 + nj * 16 + l15] = acc[mi][nj][j];
            }
}

// ---------------------------------------------------------------------------
// Fused causal depthwise conv (K=4), 4 consecutive columns, reading bf16 xBCzA.
// ---------------------------------------------------------------------------
__device__ __forceinline__ float4 conv4v(const bf16_t* __restrict__ xb, long m, int l,
                                         int col, const float* __restrict__ cw,
                                         const float* __restrict__ cbv)
{
    float4 acc = *reinterpret_cast<const float4*>(cbv + col);
    float4 wc0 = *reinterpret_cast<const float4*>(cw + (long)col * 4);
    float4 wc1 = *reinterpret_cast<const float4*>(cw + (long)col * 4 + 4);
    float4 wc2 = *reinterpret_cast<const float4*>(cw + (long)col * 4 + 8);
    float4 wc3 = *reinterpret_cast<const float4*>(cw + (long)col * 4 + 12);
    const float t0[4] = {wc0.x, wc0.y, wc0.z, wc0.w};
    const float t1[4] = {wc1.x, wc1.y, wc1.z, wc1.w};
    const float t2[4] = {wc2.x, wc2.y, wc2.z, wc2.w};
    const float t3[4] = {wc3.x, wc3.y, wc3.z, wc3.w};
    #pragma unroll
    for (int tap = 0; tap < 4; ++tap) {
        if (l - 3 + tap < 0) continue;
        const bf16_t* p = xb + (m - 3 + tap) * (long)IN_OUT + col;
        ushort4 v = *reinterpret_cast<const ushort4*>(p);
        acc.x = fmaf(b2f(v.x), t0[tap], acc.x);
        acc.y = fmaf(b2f(v.y), t1[tap], acc.y);
        acc.z = fmaf(b2f(v.z), t2[tap], acc.z);
        acc.w = fmaf(b2f(v.w), t3[tap], acc.w);
    }
    return acc;
}

// ---------------------------------------------------------------------------
// Phase A (MFMA): 512 threads / 8 waves. In-place LDS transpose (32.6 KB LDS,
// 3 blocks/CU): sx/sBr staged row-major (SWZ64), re-written in place as
// x^T / B^T*decay (SWZ128). Inline split-K partial sum + softplus for dt.
// ---------------------------------------------------------------------------
template<bool EXP>
__global__ __launch_bounds__(512, 6) void ssd_states(const bf16_t* __restrict__ xb,
                                                     const float* __restrict__ P,
                                                     const float* __restrict__ cw,
                                                     const float* __restrict__ cbv,
                                                     bf16_t* __restrict__ states,
                                                     float* __restrict__ cumbuf,
                                                     float* __restrict__ cdecay,
                                                     bf16_t* __restrict__ xtg,
                                                     bf16_t* __restrict__ bg)
{
    const int h = blockIdx.x, c = blockIdx.y, b = blockIdx.z;
    __shared__ bf16_t sx [128 * 64];   // x rows (SWZ64) -> x^T (SWZ128)
    __shared__ bf16_t sBr[128 * 64];   // B rows (SWZ64) -> B^T*decay (SWZ128)
    __shared__ float  cum[CHUNK];
    __shared__ float  w0tot;
    const int t = threadIdx.x;
    const long mbase = (long)b * SEQ + (long)c * CHUNK;
    const long cb = ((long)b * NCHUNK + c) * N_QK + h;

    // dt = softplus(sum of 4 K-slice partials); wave-level inclusive scan
    float v = 0.f;
    if (t < CHUNK) {
        const long n = (long)M_ROWS * 32;
        const long pi = (mbase + t) * N_V + h;
        const float a = P[pi] + P[n + pi] + P[2 * n + pi] + P[3 * n + pi];
        v = -((a > 20.f) ? a : log1pf(expf(a)));
        #pragma unroll
        for (int s = 1; s < 64; s <<= 1) {
            const float u2 = __shfl_up(v, s, 64);
            if ((t & 63) >= s) v += u2;
        }
        if (t == 63) w0tot = v;
    }
    for (int idx = t; idx < CHUNK * 16; idx += 512) {
        const int k = idx >> 4, q4 = (idx & 15) * 4;
        const long m = mbase + k;
        const int l = (int)(m & (SEQ - 1));
        float4 xv = conv4v(xb, m, l, h * 64 + q4, cw, cbv);
        float4 bv = conv4v(xb, m, l, D_INNER + h * 64 + q4, cw, cbv);
        store4b(&sx [SWZ64(k, q4)], xv);
        store4b(&sBr[SWZ64(k, q4)], bv);
    }
    __syncthreads();   // B1: staging + w0tot visible
    if (t >= 64 && t < CHUNK) v += w0tot;
    if (t < CHUNK) cum[t] = v;
    // read phase: pull this thread's transpose chunks to regs; export B (EXP)
    const int j = t & 127;
    const int c8b = (t >> 7) * 2;
    bf16x8 rx[2], rb[2];
    #pragma unroll
    for (int it = 0; it < 2; ++it) {
        rx[it] = *reinterpret_cast<const bf16x8*>(&sx [SWZ64(j, (c8b + it) * 8)]);
        rb[it] = *reinterpret_cast<const bf16x8*>(&sBr[SWZ64(j, (c8b + it) * 8)]);
    }
    if constexpr (EXP) {
        #pragma unroll
        for (int it = 0; it < 2; ++it) {
            const int s = it * 512 + t;   // 1024 chunks, row-major B
            *reinterpret_cast<bf16x8*>(bg + cb * 8192 + s * 8) =
                *reinterpret_cast<const bf16x8*>(&sBr[s * 8]);
        }
    }
    __syncthreads();   // B2: all reads done; cum visible
    const float clast = cum[CHUNK - 1];
    const float ej = __expf(clast - cum[j]);
    #pragma unroll
    for (int it = 0; it < 2; ++it) {
        const int c8 = c8b + it;
        #pragma unroll
        for (int e = 0; e < 8; ++e) {
            sx [SWZ128(c8 * 8 + e, j)] = rx[it][e];
            sBr[SWZ128(c8 * 8 + e, j)] = f2b(b2f((bf16_t)rb[it][e]) * ej);
        }
    }
    __syncthreads();   // B3: transposed buffers ready

    if constexpr (EXP) {
        #pragma unroll
        for (int it = 0; it < 2; ++it) {
            const int s = it * 512 + t;   // x^T, SWZ128-physical
            *reinterpret_cast<bf16x8*>(xtg + cb * 8192 + s * 8) =
                *reinterpret_cast<const bf16x8*>(&sx[s * 8]);
        }
    }

    const int lane = t & 63, wv = t >> 6;       // wv 0..7
    const int l15 = lane & 15, l4 = lane >> 4;
    const int prow  = (wv & 3) * 16;
    const int nbase = (wv >> 2) * 2;
    f32x4 acc[2];
    acc[0] = (f32x4){0.f, 0.f, 0.f, 0.f};
    acc[1] = (f32x4){0.f, 0.f, 0.f, 0.f};
    #pragma unroll
    for (int ks = 0; ks < 4; ++ks) {
        const int kc = ks * 32 + l4 * 8;
        bf16x8 af = *reinterpret_cast<const bf16x8*>(&sx[SWZ128(prow + l15, kc)]);
        #pragma unroll
        for (int nj = 0; nj < 2; ++nj) {
            bf16x8 bf = *reinterpret_cast<const bf16x8*>(&sBr[SWZ128((nbase + nj) * 16 + l15, kc)]);
            acc[nj] = __builtin_amdgcn_mfma_f32_16x16x32_bf16(af, bf, acc[nj], 0, 0, 0);
        }
    }
    #pragma unroll
    for (int nj = 0; nj < 2; ++nj) {
        #pragma unroll
        for (int jj = 0; jj < 4; ++jj) {
            const int p = prow + l4 * 4 + jj;
            states[cb * 4096 + SWZ64(p, (nbase + nj) * 16 + l15)] = f2b(acc[nj][jj]);
        }
    }
    if (t < CHUNK) cumbuf[cb * CHUNK + t] = cum[t];
    if (t == 0)   cdecay[cb] = __expf(clast);
}

// ---------------------------------------------------------------------------
// Phase B: inter-chunk scan, LDS-staged, 8 slices per (b,h) (512 blocks).
// ---------------------------------------------------------------------------
__global__ __launch_bounds__(256) void ssd_scan(bf16_t* __restrict__ states,
                                                const float* __restrict__ cdecay)
{
    const int bid = blockIdx.x;
    const int bh = bid >> 3, q = bid & 7;
    const int b = bh >> 5, h = bh & 31;
    const int t = threadIdx.x;
    __shared__ bf16_t sst[NCHUNK * 512];   // 32 KiB
    __shared__ float  scd[NCHUNK];
    if (t < NCHUNK) scd[t] = cdecay[((long)b * NCHUNK + t) * N_QK + h];
    #pragma unroll
    for (int it = 0; it < 8; ++it) {
        const int slot = it * 256 + t;          // 2048 slots x 16B
        const int c = slot >> 6, off = (slot & 63) * 8;
        const long g = (((long)b * NCHUNK + c) * N_QK + h) * 4096 + q * 512 + off;
        gload_lds16(states + g, &sst[slot * 8]);
    }
    __syncthreads();
    float2 carry = make_float2(0.f, 0.f);
    for (int c = 0; c < NCHUNK; ++c) {
        ushort2* p = reinterpret_cast<ushort2*>(&sst[c * 512 + t * 2]);
        const ushort2 su = *p;
        ushort2 pv;
        pv.x = f2b(carry.x); pv.y = f2b(carry.y);
        *p = pv;
        const float cd = scd[c];
        carry.x = fmaf(carry.x, cd, b2f(su.x));
        carry.y = fmaf(carry.y, cd, b2f(su.y));
    }
    __syncthreads();
    #pragma unroll
    for (int it = 0; it < 8; ++it) {
        const int slot = it * 256 + t;
        const int c = slot >> 6, off = (slot & 63) * 8;
        const long g = (((long)b * NCHUNK + c) * N_QK + h) * 4096 + q * 512 + off;
        *reinterpret_cast<bf16x8*>(states + g) =
            *reinterpret_cast<const bf16x8*>(&sst[slot * 8]);
    }
}

// ---------------------------------------------------------------------------
// Phase C (MFMA): 512 threads / 8 waves, each owning 16 output rows.
// ---------------------------------------------------------------------------
template<bool EXP>
__global__ __launch_bounds__(512, 4) void ssd_out(const bf16_t* __restrict__ xb,
                                                  const float* __restrict__ cumbuf,
                                                  const bf16_t* __restrict__ prevst,
                                                  const float* __restrict__ Dvec,
                                                  const float* __restrict__ zbias,
                                                  const float* __restrict__ cw,
                                                  const float* __restrict__ cbv,
                                                  const bf16_t* __restrict__ xtg,
                                                  const bf16_t* __restrict__ bg,
                                                  bf16_t* __restrict__ yz)
{
    const int h = blockIdx.x, c = blockIdx.y, b = blockIdx.z;
    __shared__ bf16_t sC[128 * 64];
    __shared__ bf16_t sB[128 * 64];
    __shared__ bf16_t sXQ[128 * 64];   // x tile (FB) / Q scratch
    __shared__ bf16_t sXT[64 * 128];   // x^T
    __shared__ bf16_t sP[64 * 64];     // prev state (bf16, SWZ64-physical)
    __shared__ float  cum[CHUNK];
    const int t = threadIdx.x;
    const long mbase = (long)b * SEQ + (long)c * CHUNK;
    const long cb = ((long)b * NCHUNK + c) * N_QK + h;
    if (t < CHUNK) cum[t] = cumbuf[cb * CHUNK + t];
    gload_lds16(prevst + cb * 4096 + t * 8, &sP[t * 8]);
    if constexpr (EXP) {
        #pragma unroll
        for (int it = 0; it < 2; ++it) {
            const int s = it * 512 + t;
            gload_lds16(bg  + cb * 8192 + s * 8, &sB [s * 8]);
            gload_lds16(xtg + cb * 8192 + s * 8, &sXT[s * 8]);
        }
        for (int idx = t; idx < CHUNK * 16; idx += 512) {
            const int k = idx >> 4, q4 = (idx & 15) * 4;
            const long m = mbase + k;
            const int l = (int)(m & (SEQ - 1));
            float4 cv = conv4v(xb, m, l, 2 * D_INNER + h * 64 + q4, cw, cbv);
            store4b(&sC[SWZ64(k, q4)], cv);
        }
        __syncthreads();
    } else {
        for (int idx = t; idx < CHUNK * 16; idx += 512) {
            const int k = idx >> 4, q4 = (idx & 15) * 4;
            const long m = mbase + k;
            const int l = (int)(m & (SEQ - 1));
            float4 xv = conv4v(xb, m, l, h * 64 + q4, cw, cbv);
            float4 bv = conv4v(xb, m, l, D_INNER + h * 64 + q4, cw, cbv);
            float4 cv = conv4v(xb, m, l, 2 * D_INNER + h * 64 + q4, cw, cbv);
            store4b(&sXQ[SWZ64(k, q4)], xv);
            store4b(&sB [SWZ64(k, q4)], bv);
            store4b(&sC [SWZ64(k, q4)], cv);
        }
        __syncthreads();
        {
            const int j = t & 127;
            const int c8b = (t >> 7) * 2;
            #pragma unroll
            for (int it = 0; it < 2; ++it) {
                const int c8 = c8b + it;
                bf16x8 v = *reinterpret_cast<const bf16x8*>(&sXQ[SWZ64(j, c8 * 8)]);
                #pragma unroll
                for (int e = 0; e < 8; ++e) sXT[SWZ128(c8 * 8 + e, j)] = v[e];
            }
        }
        __syncthreads();
    }

    const int lane = t & 63, wv = t >> 6;       // wv 0..7
    const int w16 = wv * 16, l15 = lane & 15, l4 = lane >> 4;
    bf16_t* sQ = sXQ;

    f32x4 yac[4], iac[4];
    #pragma unroll
    for (int np = 0; np < 4; ++np) {
        yac[np] = (f32x4){0.f, 0.f, 0.f, 0.f};
        iac[np] = (f32x4){0.f, 0.f, 0.f, 0.f};
    }

    #pragma unroll
    for (int H = 0; H < 2; ++H) {
        if (H == 1 && wv < 4) break;
        const int j0 = H * 64;
        f32x4 sac[4];
        #pragma unroll
        for (int nj = 0; nj < 4; ++nj) sac[nj] = (f32x4){0.f, 0.f, 0.f, 0.f};
        #pragma unroll
        for (int kk = 0; kk < 2; ++kk) {
            const int kc = kk * 32 + l4 * 8;
            bf16x8 af0 = *reinterpret_cast<const bf16x8*>(&sC[SWZ64(w16 + l15, kc)]);
            #pragma unroll
            for (int nj = 0; nj < 4; ++nj) {
                if (j0 + nj * 16 <= w16 + 15) {
                    bf16x8 bfj = *reinterpret_cast<const bf16x8*>(&sB[SWZ64(j0 + nj * 16 + l15, kc)]);
                    sac[nj] = __builtin_amdgcn_mfma_f32_16x16x32_bf16(af0, bfj, sac[nj], 0, 0, 0);
                }
            }
        }
        #pragma unroll
        for (int nj = 0; nj < 4; ++nj) {
            const int jcol = nj * 16 + l15;
            const int jg = j0 + jcol;
            #pragma unroll
            for (int jj = 0; jj < 4; ++jj) {
                const int i = w16 + l4 * 4 + jj;
                const float q = (jg <= i) ? __expf(cum[i] - cum[jg]) * sac[nj][jj] : 0.f;
                sQ[SWZ64(i, jcol)] = f2b(q);
            }
        }
        #pragma unroll
        for (int kk = 0; kk < 2; ++kk) {
            const int kc = kk * 32 + l4 * 8;
            bf16x8 qa = *reinterpret_cast<const bf16x8*>(&sQ[SWZ64(w16 + l15, kc)]);
            #pragma unroll
            for (int np = 0; np < 4; ++np) {
                bf16x8 xf = *reinterpret_cast<const bf16x8*>(&sXT[SWZ128(np * 16 + l15, j0 + kc)]);
                yac[np] = __builtin_amdgcn_mfma_f32_16x16x32_bf16(qa, xf, yac[np], 0, 0, 0);
            }
        }
    }
    #pragma unroll
    for (int kk = 0; kk < 2; ++kk) {
        const int kc = kk * 32 + l4 * 8;
        bf16x8 cf = *reinterpret_cast<const bf16x8*>(&sC[SWZ64(w16 + l15, kc)]);
        #pragma unroll
        for (int np = 0; np < 4; ++np) {
            bf16x8 pf = *reinterpret_cast<const bf16x8*>(&sP[SWZ64(np * 16 + l15, kc)]);
            iac[np] = __builtin_amdgcn_mfma_f32_16x16x32_bf16(cf, pf, iac[np], 0, 0, 0);
        }
    }
    const float dh = Dvec[h];
    #pragma unroll
    for (int jj = 0; jj < 4; ++jj) {
        const int i = w16 + l4 * 4 + jj;
        const float ei = __expf(cum[i]);
        const long m = mbase + i;
        const bf16_t* zr = xb + m * (long)IN_OUT + CONV_DIM + h * 64;
        bf16_t* orow = yz + m * (long)D_INNER + h * 64;
        #pragma unroll
        for (int np = 0; np < 4; ++np) {
            const int p = np * 16 + l15;
            const float xval = b2f(sXT[SWZ128(p, i)]);
            const float y = yac[np][jj] + ei * iac[np][jj] + dh * xval;
            const float zv = b2f(zr[p]) + zbias[h * 64 + p];
            const float s = zv / (1.f + __expf(-zv));
            orow[p] = f2b(y * s);
        }
    }
}

// ---------------------------------------------------------------------------
extern "C" void kernel_launch(void* const* d_in, const int* in_sizes, int n_in,
                              void* d_out, int out_size, void* d_ws, size_t ws_size,
                              hipStream_t stream)
{
    const float* u      = (const float*)d_in[0];
    const float* W_in   = (const float*)d_in[1];
    const float* conv_w = (const float*)d_in[2];
    const float* conv_b = (const float*)d_in[3];
    const float* Dv     = (const float*)d_in[4];
    const float* z_bias = (const float*)d_in[5];
    const float* W_out  = (const float*)d_in[6];
    float* out = (float*)d_out;

    char* w = (char*)d_ws;
    bf16_t* xbcza = (bf16_t*)w;  w += (long)M_ROWS * IN_OUT * 2;   // 128.5 MiB
    bf16_t* wob   = (bf16_t*)w;  w += (long)2048 * 2048 * 2;       //   8 MiB
    char* ureg = w;  w += 67239936;                                 // 64.1 MiB union
    bf16_t* ub  = (bf16_t*)ureg;                                    // 32 MiB (phase 1)
    bf16_t* wib = (bf16_t*)(ureg + (long)M_ROWS * D_MODEL * 2);     // 32.125 MiB (phase 1)
    bf16_t* yzb = (bf16_t*)ureg;                                    // 32 MiB (phase 2)
    float*  cumb   = (float*)(ureg + (long)M_ROWS * D_INNER * 2);   //  1 MiB @ureg+32MiB
    bf16_t* states = (bf16_t*)(cumb + (long)BATCH * NCHUNK * N_QK * CHUNK); // 16 MiB @33..49MiB
    float*  cdec   = (float*)(states + (long)BATCH * NCHUNK * N_QK * 4096); //  8 KiB
    // A_log split-K partials @ ureg+56MiB (4 MiB): wib rows 6144..7167 (dead
    // after gemm1); clear of states [33,49)MiB since read concurrently by
    // ssd_states while it writes states.
    float* partials = (float*)(ureg + 58720256);
    const long base_bytes = (long)(w - (char*)d_ws);
    const long exp_bytes  = 2L * 2048 * 8192 * 2;                   // xtg + bg
    const bool use_exp = ((long)ws_size >= base_bytes + exp_bytes);
    bf16_t* xtg = (bf16_t*)w;
    bf16_t* bg  = xtg + (long)2048 * 8192;

    // fused fp32->bf16 conversions (u, W_in, W_out), grid-stride
    {
        const long n0 = (long)M_ROWS * D_MODEL;
        const long n1 = (long)IN_OUT * D_MODEL;
        const long n2 = (long)D_MODEL * D_INNER;
        f2b3_kernel<<<2048, 256, 0, stream>>>(u, ub, n0, W_in, wib, n1, W_out, wob, n2);
    }

    // GEMM1 main: cols [0, 8192), 1024 wgs, bm-major
    gemm256<32, D_MODEL, true><<<(M_ROWS / 256) * 32, 512, 0, stream>>>(
        ub, wib, xbcza, IN_OUT);

    // A_log tail -> split-K partials (summed + softplus'd inside ssd_states)
    alog_partial<<<256, 256, 0, stream>>>(ub, wib + (long)8192 * D_MODEL, partials);

    if (use_exp) {
        ssd_states<true><<<dim3(N_QK, NCHUNK, BATCH), 512, 0, stream>>>(
            xbcza, partials, conv_w, conv_b, states, cumb, cdec, xtg, bg);
        ssd_scan<<<BATCH * N_QK * 8, 256, 0, stream>>>(states, cdec);
        ssd_out<true><<<dim3(N_QK, NCHUNK, BATCH), 512, 0, stream>>>(
            xbcza, cumb, states, Dv, z_bias, conv_w, conv_b, xtg, bg, yzb);
    } else {
        ssd_states<false><<<dim3(N_QK, NCHUNK, BATCH), 512, 0, stream>>>(
            xbcza, partials, conv_w, conv_b, states, cumb, cdec, nullptr, nullptr);
        ssd_scan<<<BATCH * N_QK * 8, 256, 0, stream>>>(states, cdec);
        ssd_out<false><<<dim3(N_QK, NCHUNK, BATCH), 512, 0, stream>>>(
            xbcza, cumb, states, Dv, z_bias, conv_w, conv_b, nullptr, nullptr, yzb);
    }

    // GEMM2: out = yz @ W_out^T  (8192 x 2048 x 2048), 256 wgs
    gemm256<8, D_INNER, false><<<(M_ROWS / 256) * 8, 512, 0, stream>>>(
        yzb, wob, out, D_MODEL);
}

// Round 18
// 708.902 us; speedup vs baseline: 1.0667x; 1.0005x over previous
//
#include <hip/hip_runtime.h>
#include <math.h>

#define D_MODEL  2048
#define D_INNER  2048
#define N_QK     32
#define N_V      32
#define D_STATE  64
#define D_CONV   4
#define CHUNK    128
#define CONV_DIM 6144      // D_INNER + 2*N_QK*D_STATE
#define IN_OUT   8224      // 2*D_INNER + 2*N_QK*D_STATE + N_V
#define BATCH    2
#define SEQ      4096
#define M_ROWS   (BATCH*SEQ)   // 8192
#define NCHUNK   (SEQ/CHUNK)   // 32

typedef unsigned short bf16_t;
typedef __attribute__((ext_vector_type(4))) float f32x4;
typedef __attribute__((ext_vector_type(8))) short bf16x8;

// swizzled row-major LDS index (elem units); XOR bits 3-5 spread rows over banks
#define SWZ64(r,c)  ((((r)*64)  + (c)) ^ (((r)&7)<<3))
#define SWZ128(r,c) ((((r)*128) + (c)) ^ (((r)&7)<<3))

__device__ __forceinline__ float b2f(bf16_t u) {
    union { unsigned int i; float f; } w; w.i = ((unsigned int)u) << 16; return w.f;
}
__device__ __forceinline__ bf16_t f2b(float f) {
    unsigned int x = __float_as_uint(f);
    return (bf16_t)((x + 0x7FFFu + ((x >> 16) & 1u)) >> 16);   // RNE
}
__device__ __forceinline__ void store4b(bf16_t* dst, float4 v) {
    ushort4 u; u.x = f2b(v.x); u.y = f2b(v.y); u.z = f2b(v.z); u.w = f2b(v.w);
    *reinterpret_cast<ushort4*>(dst) = u;
}

__device__ __forceinline__ void gload_lds16(const bf16_t* g, bf16_t* l) {
    __builtin_amdgcn_global_load_lds((const __attribute__((address_space(1))) void*)g,
                                     (__attribute__((address_space(3))) void*)l,
                                     16, 0, 0);
}

// ---------------------------------------------------------------------------
// fused fp32 -> bf16 convert (grid-stride, 2048 blocks)
// ---------------------------------------------------------------------------
__global__ __launch_bounds__(256) void f2b3_kernel(const float* __restrict__ a0, bf16_t* __restrict__ o0, long n0,
                                                   const float* __restrict__ a1, bf16_t* __restrict__ o1, long n1,
                                                   const float* __restrict__ a2, bf16_t* __restrict__ o2, long n2)
{
    const long total = (n0 + n1 + n2) >> 2;
    for (long s = (long)blockIdx.x * 256 + threadIdx.x; s < total; s += (long)gridDim.x * 256) {
        long i = s << 2;
        const float* in; bf16_t* out;
        if (i < n0)           { in = a0 + i; out = o0 + i; }
        else if (i < n0 + n1) { i -= n0; in = a1 + i; out = o1 + i; }
        else                  { i -= n0 + n1; in = a2 + i; out = o2 + i; }
        float4 v = *reinterpret_cast<const float4*>(in);
        ushort4 o;
        o.x = f2b(v.x); o.y = f2b(v.y); o.z = f2b(v.z); o.w = f2b(v.w);
        *reinterpret_cast<ushort4*>(out) = o;
    }
}

// ---------------------------------------------------------------------------
// 256x256 bf16 MFMA NT-GEMM, K-half counted-vmcnt pipeline, 2 barriers/tile.
// (R12/R13-proven structure -- do not touch.)
// ---------------------------------------------------------------------------
template<int NTB, int K, bool OBF16>
__global__ __launch_bounds__(512, 2) void gemm256(const bf16_t* __restrict__ A,
                                                  const bf16_t* __restrict__ B,
                                                  void* __restrict__ Cv,
                                                  long ldc)
{
    constexpr int BK = 64;
    constexpr int NT = K / BK;
    __shared__ bf16_t As[2][2][8192];   // [buf][kh][1024 slots * 8 elems]
    __shared__ bf16_t Bs[2][2][8192];

    const int nwg = gridDim.x;
    const int bid = blockIdx.x;
    const int wg  = ((nwg & 7) == 0) ? ((bid & 7) * (nwg >> 3) + (bid >> 3)) : bid;
    const int bm = (wg / NTB) * 256;
    const int bn = (wg % NTB) * 256;

    const int tid  = threadIdx.x;
    const int lane = tid & 63;
    const int wv   = tid >> 6;
    const int wr   = wv >> 2, wc = wv & 3;       // 2x4 wave grid
    const int l15  = lane & 15, l4 = lane >> 4;

    f32x4 acc[8][4];
    #pragma unroll
    for (int i = 0; i < 8; ++i)
        #pragma unroll
        for (int j = 0; j < 4; ++j) acc[i][j] = (f32x4){0.f, 0.f, 0.f, 0.f};

    const bf16_t* Abase = A + (long)bm * K;
    const bf16_t* Bbase = B + (long)bn * K;

    auto stage_half = [&](int t, int buf, int kh) {
        #pragma unroll
        for (int it = 0; it < 2; ++it) {
            const int s   = it * 512 + tid;          // 0..1023
            const int row = s >> 2;                  // 0..255
            const int jp  = s & 3;                   // physical chunk in half
            const int jl  = jp ^ ((row >> 1) & 3);   // logical chunk in half
            const long go = (long)row * K + t * BK + kh * 32 + jl * 8;
            gload_lds16(Abase + go, &As[buf][kh][s * 8]);
            gload_lds16(Bbase + go, &Bs[buf][kh][s * 8]);
        }
    };
    auto rdA = [&](int buf, int kh, int row) {
        const int jp = l4 ^ ((row >> 1) & 3);
        return *reinterpret_cast<const bf16x8*>(&As[buf][kh][(row * 4 + jp) * 8]);
    };
    auto rdB = [&](int buf, int kh, int row) {
        const int jp = l4 ^ ((row >> 1) & 3);
        return *reinterpret_cast<const bf16x8*>(&Bs[buf][kh][(row * 4 + jp) * 8]);
    };

    stage_half(0, 0, 0);
    stage_half(0, 0, 1);
    asm volatile("s_waitcnt vmcnt(4)" ::: "memory");   // K-half0 of tile 0 landed
    __builtin_amdgcn_s_barrier();

    for (int t = 0; t < NT; ++t) {
        const int cur = t & 1;
        bf16x8 bfr[4], af[4];
        if (t + 1 < NT) stage_half(t + 1, cur ^ 1, 0);
        // K-half 0: qm=0 then qm=1
        #pragma unroll
        for (int ni = 0; ni < 4; ++ni) bfr[ni] = rdB(cur, 0, wc * 64 + ni * 16 + l15);
        #pragma unroll
        for (int mi = 0; mi < 4; ++mi) af[mi] = rdA(cur, 0, wr * 128 + mi * 16 + l15);
        __builtin_amdgcn_s_setprio(1);
        #pragma unroll
        for (int mi = 0; mi < 4; ++mi)
            #pragma unroll
            for (int ni = 0; ni < 4; ++ni)
                acc[mi][ni] = __builtin_amdgcn_mfma_f32_16x16x32_bf16(
                    af[mi], bfr[ni], acc[mi][ni], 0, 0, 0);
        __builtin_amdgcn_s_setprio(0);
        #pragma unroll
        for (int mi = 0; mi < 4; ++mi) af[mi] = rdA(cur, 0, wr * 128 + 64 + mi * 16 + l15);
        __builtin_amdgcn_s_setprio(1);
        #pragma unroll
        for (int mi = 0; mi < 4; ++mi)
            #pragma unroll
            for (int ni = 0; ni < 4; ++ni)
                acc[4 + mi][ni] = __builtin_amdgcn_mfma_f32_16x16x32_bf16(
                    af[mi], bfr[ni], acc[4 + mi][ni], 0, 0, 0);
        __builtin_amdgcn_s_setprio(0);
        if (t + 1 < NT) {
            stage_half(t + 1, cur ^ 1, 1);
            asm volatile("s_waitcnt vmcnt(8)" ::: "memory");   // K1(t) landed
        } else {
            asm volatile("s_waitcnt vmcnt(0)" ::: "memory");
        }
        __builtin_amdgcn_s_barrier();
        // K-half 1: qm=0 then qm=1
        #pragma unroll
        for (int ni = 0; ni < 4; ++ni) bfr[ni] = rdB(cur, 1, wc * 64 + ni * 16 + l15);
        #pragma unroll
        for (int mi = 0; mi < 4; ++mi) af[mi] = rdA(cur, 1, wr * 128 + mi * 16 + l15);
        __builtin_amdgcn_s_setprio(1);
        #pragma unroll
        for (int mi = 0; mi < 4; ++mi)
            #pragma unroll
            for (int ni = 0; ni < 4; ++ni)
                acc[mi][ni] = __builtin_amdgcn_mfma_f32_16x16x32_bf16(
                    af[mi], bfr[ni], acc[mi][ni], 0, 0, 0);
        __builtin_amdgcn_s_setprio(0);
        #pragma unroll
        for (int mi = 0; mi < 4; ++mi) af[mi] = rdA(cur, 1, wr * 128 + 64 + mi * 16 + l15);
        __builtin_amdgcn_s_setprio(1);
        #pragma unroll
        for (int mi = 0; mi < 4; ++mi)
            #pragma unroll
            for (int ni = 0; ni < 4; ++ni)
                acc[4 + mi][ni] = __builtin_amdgcn_mfma_f32_16x16x32_bf16(
                    af[mi], bfr[ni], acc[4 + mi][ni], 0, 0, 0);
        __builtin_amdgcn_s_setprio(0);
        if (t + 1 < NT) { asm volatile("s_waitcnt vmcnt(4)" ::: "memory"); }
        __builtin_amdgcn_s_barrier();
    }

    #pragma unroll
    for (int mf = 0; mf < 8; ++mf) {
        const long grow0 = bm + wr * 128 + mf * 16 + l4 * 4;
        #pragma unroll
        for (int ni = 0; ni < 4; ++ni) {
            const int gcol = bn + wc * 64 + ni * 16 + l15;
            #pragma unroll
            for (int j = 0; j < 4; ++j) {
                if (OBF16)
                    ((bf16_t*)Cv)[(grow0 + j) * ldc + gcol] = f2b(acc[mf][ni][j]);
                else
                    ((float*)Cv)[(grow0 + j) * ldc + gcol] = acc[mf][ni][j];
            }
        }
    }
}

// ---------------------------------------------------------------------------
// A_log split-K partial GEMM: P[ks][m][h] = sum_{k in slice ks} ub[m][k]*wt[h][k]
// ---------------------------------------------------------------------------
__global__ __launch_bounds__(256) void alog_partial(const bf16_t* __restrict__ A,
                                                    const bf16_t* __restrict__ Bt,
                                                    float* __restrict__ P)
{
    const int rb = blockIdx.x & 63, ks = blockIdx.x >> 6;
    const int bm = rb * 128;
    __shared__ bf16_t As[128 * 64];   // involution layout (R5-proven)
    __shared__ bf16_t Bs[32 * 64];
    const int tid = threadIdx.x, lane = tid & 63, wv = tid >> 6;
    const int l15 = lane & 15, l4 = lane >> 4;

    f32x4 acc[2][2];
    #pragma unroll
    for (int mi = 0; mi < 2; ++mi)
        #pragma unroll
        for (int nj = 0; nj < 2; ++nj) acc[mi][nj] = (f32x4){0.f, 0.f, 0.f, 0.f};

    for (int it8 = 0; it8 < 8; ++it8) {
        const long kbase = (long)ks * 512 + it8 * 64;
        #pragma unroll
        for (int it = 0; it < 4; ++it) {
            const int s = it * 256 + tid;            // 1024 slots
            const int row = s >> 3, c16 = s & 7;
            gload_lds16(A + (long)(bm + row) * D_MODEL + kbase + (c16 ^ (row & 7)) * 8,
                        &As[s * 8]);
        }
        {
            const int row = tid >> 3, c16 = tid & 7;  // 256 slots
            gload_lds16(Bt + (long)row * D_MODEL + kbase + (c16 ^ (row & 7)) * 8,
                        &Bs[tid * 8]);
        }
        __syncthreads();
        #pragma unroll
        for (int kk = 0; kk < 2; ++kk) {
            bf16x8 bf[2], af;
            #pragma unroll
            for (int nj = 0; nj < 2; ++nj) {
                const int row = nj * 16 + l15;
                bf[nj] = *reinterpret_cast<const bf16x8*>(&Bs[row * 64 + (((kk * 4 + l4) ^ (row & 7)) << 3)]);
            }
            #pragma unroll
            for (int mi = 0; mi < 2; ++mi) {
                const int row = wv * 32 + mi * 16 + l15;
                af = *reinterpret_cast<const bf16x8*>(&As[row * 64 + (((kk * 4 + l4) ^ (row & 7)) << 3)]);
                #pragma unroll
                for (int nj = 0; nj < 2; ++nj)
                    acc[mi][nj] = __builtin_amdgcn_mfma_f32_16x16x32_bf16(af, bf[nj], acc[mi][nj], 0, 0, 0);
            }
        }
        __syncthreads();
    }
    #pragma unroll
    for (int mi = 0; mi < 2; ++mi)
        #pragma unroll
        for (int nj = 0; nj < 2; ++nj)
            #pragma unroll
            for (int j = 0; j < 4; ++j) {
                const int row = bm + wv * 32 + mi * 16 + l4 * 4 + j;
                P[(long)ks * (M_ROWS * 32) + (long)row * 32 + nj * 16 + l15] = acc[mi][nj][j];
            }
}

// ---------------------------------------------------------------------------
// Fused causal depthwise conv (K=4), 4 consecutive columns, reading bf16 xBCzA.
// ---------------------------------------------------------------------------
__device__ __forceinline__ float4 conv4v(const bf16_t* __restrict__ xb, long m, int l,
                                         int col, const float* __restrict__ cw,
                                         const float* __restrict__ cbv)
{
    float4 acc = *reinterpret_cast<const float4*>(cbv + col);
    float4 wc0 = *reinterpret_cast<const float4*>(cw + (long)col * 4);
    float4 wc1 = *reinterpret_cast<const float4*>(cw + (long)col * 4 + 4);
    float4 wc2 = *reinterpret_cast<const float4*>(cw + (long)col * 4 + 8);
    float4 wc3 = *reinterpret_cast<const float4*>(cw + (long)col * 4 + 12);
    const float t0[4] = {wc0.x, wc0.y, wc0.z, wc0.w};
    const float t1[4] = {wc1.x, wc1.y, wc1.z, wc1.w};
    const float t2[4] = {wc2.x, wc2.y, wc2.z, wc2.w};
    const float t3[4] = {wc3.x, wc3.y, wc3.z, wc3.w};
    #pragma unroll
    for (int tap = 0; tap < 4; ++tap) {
        if (l - 3 + tap < 0) continue;
        const bf16_t* p = xb + (m - 3 + tap) * (long)IN_OUT + col;
        ushort4 v = *reinterpret_cast<const ushort4*>(p);
        acc.x = fmaf(b2f(v.x), t0[tap], acc.x);
        acc.y = fmaf(b2f(v.y), t1[tap], acc.y);
        acc.z = fmaf(b2f(v.z), t2[tap], acc.z);
        acc.w = fmaf(b2f(v.w), t3[tap], acc.w);
    }
    return acc;
}

// ---------------------------------------------------------------------------
// Phase A (MFMA): 512 threads / 8 waves, in-place transpose (R17-proven).
// EXPL>=1: export conv'd B + x^T. EXPL==2: also stage+export conv'd C.
// ---------------------------------------------------------------------------
template<int EXPL>
__global__ __launch_bounds__(512, 6) void ssd_states(const bf16_t* __restrict__ xb,
                                                     const float* __restrict__ P,
                                                     const float* __restrict__ cw,
                                                     const float* __restrict__ cbv,
                                                     bf16_t* __restrict__ states,
                                                     float* __restrict__ cumbuf,
                                                     float* __restrict__ cdecay,
                                                     bf16_t* __restrict__ xtg,
                                                     bf16_t* __restrict__ bg,
                                                     bf16_t* __restrict__ cg)
{
    const int h = blockIdx.x, c = blockIdx.y, b = blockIdx.z;
    __shared__ bf16_t sx [128 * 64];   // x rows (SWZ64) -> x^T (SWZ128)
    __shared__ bf16_t sBr[128 * 64];   // B rows (SWZ64) -> B^T*decay (SWZ128)
    __shared__ bf16_t sC [128 * 64];   // conv'd C rows (EXPL==2 only)
    __shared__ float  cum[CHUNK];
    __shared__ float  w0tot;
    const int t = threadIdx.x;
    const long mbase = (long)b * SEQ + (long)c * CHUNK;
    const long cb = ((long)b * NCHUNK + c) * N_QK + h;

    // dt = softplus(sum of 4 K-slice partials); wave-level inclusive scan
    float v = 0.f;
    if (t < CHUNK) {
        const long n = (long)M_ROWS * 32;
        const long pi = (mbase + t) * N_V + h;
        const float a = P[pi] + P[n + pi] + P[2 * n + pi] + P[3 * n + pi];
        v = -((a > 20.f) ? a : log1pf(expf(a)));
        #pragma unroll
        for (int s = 1; s < 64; s <<= 1) {
            const float u2 = __shfl_up(v, s, 64);
            if ((t & 63) >= s) v += u2;
        }
        if (t == 63) w0tot = v;
    }
    for (int idx = t; idx < CHUNK * 16; idx += 512) {
        const int k = idx >> 4, q4 = (idx & 15) * 4;
        const long m = mbase + k;
        const int l = (int)(m & (SEQ - 1));
        float4 xv = conv4v(xb, m, l, h * 64 + q4, cw, cbv);
        float4 bv = conv4v(xb, m, l, D_INNER + h * 64 + q4, cw, cbv);
        store4b(&sx [SWZ64(k, q4)], xv);
        store4b(&sBr[SWZ64(k, q4)], bv);
        if (EXPL == 2) {
            float4 cv = conv4v(xb, m, l, 2 * D_INNER + h * 64 + q4, cw, cbv);
            store4b(&sC[SWZ64(k, q4)], cv);
        }
    }
    __syncthreads();   // B1: staging + w0tot visible
    if (t >= 64 && t < CHUNK) v += w0tot;
    if (t < CHUNK) cum[t] = v;
    // read phase: pull this thread's transpose chunks to regs; export B/C
    const int j = t & 127;
    const int c8b = (t >> 7) * 2;
    bf16x8 rx[2], rb[2];
    #pragma unroll
    for (int it = 0; it < 2; ++it) {
        rx[it] = *reinterpret_cast<const bf16x8*>(&sx [SWZ64(j, (c8b + it) * 8)]);
        rb[it] = *reinterpret_cast<const bf16x8*>(&sBr[SWZ64(j, (c8b + it) * 8)]);
    }
    if (EXPL >= 1) {
        #pragma unroll
        for (int it = 0; it < 2; ++it) {
            const int s = it * 512 + t;   // 1024 chunks, physical-linear
            *reinterpret_cast<bf16x8*>(bg + cb * 8192 + s * 8) =
                *reinterpret_cast<const bf16x8*>(&sBr[s * 8]);
            if (EXPL == 2)
                *reinterpret_cast<bf16x8*>(cg + cb * 8192 + s * 8) =
                    *reinterpret_cast<const bf16x8*>(&sC[s * 8]);
        }
    }
    __syncthreads();   // B2: all reads done; cum visible
    const float clast = cum[CHUNK - 1];
    const float ej = __expf(clast - cum[j]);
    #pragma unroll
    for (int it = 0; it < 2; ++it) {
        const int c8 = c8b + it;
        #pragma unroll
        for (int e = 0; e < 8; ++e) {
            sx [SWZ128(c8 * 8 + e, j)] = rx[it][e];
            sBr[SWZ128(c8 * 8 + e, j)] = f2b(b2f((bf16_t)rb[it][e]) * ej);
        }
    }
    __syncthreads();   // B3: transposed buffers ready

    if (EXPL >= 1) {
        #pragma unroll
        for (int it = 0; it < 2; ++it) {
            const int s = it * 512 + t;   // x^T, SWZ128-physical
            *reinterpret_cast<bf16x8*>(xtg + cb * 8192 + s * 8) =
                *reinterpret_cast<const bf16x8*>(&sx[s * 8]);
        }
    }

    const int lane = t & 63, wv = t >> 6;       // wv 0..7
    const int l15 = lane & 15, l4 = lane >> 4;
    const int prow  = (wv & 3) * 16;
    const int nbase = (wv >> 2) * 2;
    f32x4 acc[2];
    acc[0] = (f32x4){0.f, 0.f, 0.f, 0.f};
    acc[1] = (f32x4){0.f, 0.f, 0.f, 0.f};
    #pragma unroll
    for (int ks = 0; ks < 4; ++ks) {
        const int kc = ks * 32 + l4 * 8;
        bf16x8 af = *reinterpret_cast<const bf16x8*>(&sx[SWZ128(prow + l15, kc)]);
        #pragma unroll
        for (int nj = 0; nj < 2; ++nj) {
            bf16x8 bf = *reinterpret_cast<const bf16x8*>(&sBr[SWZ128((nbase + nj) * 16 + l15, kc)]);
            acc[nj] = __builtin_amdgcn_mfma_f32_16x16x32_bf16(af, bf, acc[nj], 0, 0, 0);
        }
    }
    #pragma unroll
    for (int nj = 0; nj < 2; ++nj) {
        #pragma unroll
        for (int jj = 0; jj < 4; ++jj) {
            const int p = prow + l4 * 4 + jj;
            states[cb * 4096 + SWZ64(p, (nbase + nj) * 16 + l15)] = f2b(acc[nj][jj]);
        }
    }
    if (t < CHUNK) cumbuf[cb * CHUNK + t] = cum[t];
    if (t == 0)   cdecay[cb] = __expf(clast);
}

// ---------------------------------------------------------------------------
// Phase B: inter-chunk scan, LDS-staged, 8 slices per (b,h) (512 blocks).
// ---------------------------------------------------------------------------
__global__ __launch_bounds__(256) void ssd_scan(bf16_t* __restrict__ states,
                                                const float* __restrict__ cdecay)
{
    const int bid = blockIdx.x;
    const int bh = bid >> 3, q = bid & 7;
    const int b = bh >> 5, h = bh & 31;
    const int t = threadIdx.x;
    __shared__ bf16_t sst[NCHUNK * 512];   // 32 KiB
    __shared__ float  scd[NCHUNK];
    if (t < NCHUNK) scd[t] = cdecay[((long)b * NCHUNK + t) * N_QK + h];
    #pragma unroll
    for (int it = 0; it < 8; ++it) {
        const int slot = it * 256 + t;          // 2048 slots x 16B
        const int c = slot >> 6, off = (slot & 63) * 8;
        const long g = (((long)b * NCHUNK + c) * N_QK + h) * 4096 + q * 512 + off;
        gload_lds16(states + g, &sst[slot * 8]);
    }
    __syncthreads();
    float2 carry = make_float2(0.f, 0.f);
    for (int c = 0; c < NCHUNK; ++c) {
        ushort2* p = reinterpret_cast<ushort2*>(&sst[c * 512 + t * 2]);
        const ushort2 su = *p;
        ushort2 pv;
        pv.x = f2b(carry.x); pv.y = f2b(carry.y);
        *p = pv;
        const float cd = scd[c];
        carry.x = fmaf(carry.x, cd, b2f(su.x));
        carry.y = fmaf(carry.y, cd, b2f(su.y));
    }
    __syncthreads();
    #pragma unroll
    for (int it = 0; it < 8; ++it) {
        const int slot = it * 256 + t;
        const int c = slot >> 6, off = (slot & 63) * 8;
        const long g = (((long)b * NCHUNK + c) * N_QK + h) * 4096 + q * 512 + off;
        *reinterpret_cast<bf16x8*>(states + g) =
            *reinterpret_cast<const bf16x8*>(&sst[slot * 8]);
    }
}

// ---------------------------------------------------------------------------
// Phase C (MFMA): 512 threads / 8 waves, each owning 16 output rows.
// EXPL==2: C also staged via global_load_lds (no conv at all here).
// ---------------------------------------------------------------------------
template<int EXPL>
__global__ __launch_bounds__(512, 4) void ssd_out(const bf16_t* __restrict__ xb,
                                                  const float* __restrict__ cumbuf,
                                                  const bf16_t* __restrict__ prevst,
                                                  const float* __restrict__ Dvec,
                                                  const float* __restrict__ zbias,
                                                  const float* __restrict__ cw,
                                                  const float* __restrict__ cbv,
                                                  const bf16_t* __restrict__ xtg,
                                                  const bf16_t* __restrict__ bg,
                                                  const bf16_t* __restrict__ cg,
                                                  bf16_t* __restrict__ yz)
{
    const int h = blockIdx.x, c = blockIdx.y, b = blockIdx.z;
    __shared__ bf16_t sC[128 * 64];
    __shared__ bf16_t sB[128 * 64];
    __shared__ bf16_t sXQ[128 * 64];   // x tile (FB) / Q scratch
    __shared__ bf16_t sXT[64 * 128];   // x^T
    __shared__ bf16_t sP[64 * 64];     // prev state (bf16, SWZ64-physical)
    __shared__ float  cum[CHUNK];
    const int t = threadIdx.x;
    const long mbase = (long)b * SEQ + (long)c * CHUNK;
    const long cb = ((long)b * NCHUNK + c) * N_QK + h;
    if (t < CHUNK) cum[t] = cumbuf[cb * CHUNK + t];
    gload_lds16(prevst + cb * 4096 + t * 8, &sP[t * 8]);
    if (EXPL == 2) {
        #pragma unroll
        for (int it = 0; it < 2; ++it) {
            const int s = it * 512 + t;
            gload_lds16(bg  + cb * 8192 + s * 8, &sB [s * 8]);
            gload_lds16(xtg + cb * 8192 + s * 8, &sXT[s * 8]);
            gload_lds16(cg  + cb * 8192 + s * 8, &sC [s * 8]);
        }
        __syncthreads();
    } else if (EXPL == 1) {
        #pragma unroll
        for (int it = 0; it < 2; ++it) {
            const int s = it * 512 + t;
            gload_lds16(bg  + cb * 8192 + s * 8, &sB [s * 8]);
            gload_lds16(xtg + cb * 8192 + s * 8, &sXT[s * 8]);
        }
        for (int idx = t; idx < CHUNK * 16; idx += 512) {
            const int k = idx >> 4, q4 = (idx & 15) * 4;
            const long m = mbase + k;
            const int l = (int)(m & (SEQ - 1));
            float4 cv = conv4v(xb, m, l, 2 * D_INNER + h * 64 + q4, cw, cbv);
            store4b(&sC[SWZ64(k, q4)], cv);
        }
        __syncthreads();
    } else {
        for (int idx = t; idx < CHUNK * 16; idx += 512) {
            const int k = idx >> 4, q4 = (idx & 15) * 4;
            const long m = mbase + k;
            const int l = (int)(m & (SEQ - 1));
            float4 xv = conv4v(xb, m, l, h * 64 + q4, cw, cbv);
            float4 bv = conv4v(xb, m, l, D_INNER + h * 64 + q4, cw, cbv);
            float4 cv = conv4v(xb, m, l, 2 * D_INNER + h * 64 + q4, cw, cbv);
            store4b(&sXQ[SWZ64(k, q4)], xv);
            store4b(&sB [SWZ64(k, q4)], bv);
            store4b(&sC [SWZ64(k, q4)], cv);
        }
        __syncthreads();
        {
            const int j = t & 127;
            const int c8b = (t >> 7) * 2;
            #pragma unroll
            for (int it = 0; it < 2; ++it) {
                const int c8 = c8b + it;
                bf16x8 v = *reinterpret_cast<const bf16x8*>(&sXQ[SWZ64(j, c8 * 8)]);
                #pragma unroll
                for (int e = 0; e < 8; ++e) sXT[SWZ128(c8 * 8 + e, j)] = v[e];
            }
        }
        __syncthreads();
    }

    const int lane = t & 63, wv = t >> 6;       // wv 0..7
    const int w16 = wv * 16, l15 = lane & 15, l4 = lane >> 4;
    bf16_t* sQ = sXQ;

    f32x4 yac[4], iac[4];
    #pragma unroll
    for (int np = 0; np < 4; ++np) {
        yac[np] = (f32x4){0.f, 0.f, 0.f, 0.f};
        iac[np] = (f32x4){0.f, 0.f, 0.f, 0.f};
    }

    #pragma unroll
    for (int H = 0; H < 2; ++H) {
        if (H == 1 && wv < 4) break;
        const int j0 = H * 64;
        f32x4 sac[4];
        #pragma unroll
        for (int nj = 0; nj < 4; ++nj) sac[nj] = (f32x4){0.f, 0.f, 0.f, 0.f};
        #pragma unroll
        for (int kk = 0; kk < 2; ++kk) {
            const int kc = kk * 32 + l4 * 8;
            bf16x8 af0 = *reinterpret_cast<const bf16x8*>(&sC[SWZ64(w16 + l15, kc)]);
            #pragma unroll
            for (int nj = 0; nj < 4; ++nj) {
                if (j0 + nj * 16 <= w16 + 15) {
                    bf16x8 bfj = *reinterpret_cast<const bf16x8*>(&sB[SWZ64(j0 + nj * 16 + l15, kc)]);
                    sac[nj] = __builtin_amdgcn_mfma_f32_16x16x32_bf16(af0, bfj, sac[nj], 0, 0, 0);
                }
            }
        }
        #pragma unroll
        for (int nj = 0; nj < 4; ++nj) {
            const int jcol = nj * 16 + l15;
            const int jg = j0 + jcol;
            #pragma unroll
            for (int jj = 0; jj < 4; ++jj) {
                const int i = w16 + l4 * 4 + jj;
                const float q = (jg <= i) ? __expf(cum[i] - cum[jg]) * sac[nj][jj] : 0.f;
                sQ[SWZ64(i, jcol)] = f2b(q);
            }
        }
        #pragma unroll
        for (int kk = 0; kk < 2; ++kk) {
            const int kc = kk * 32 + l4 * 8;
            bf16x8 qa = *reinterpret_cast<const bf16x8*>(&sQ[SWZ64(w16 + l15, kc)]);
            #pragma unroll
            for (int np = 0; np < 4; ++np) {
                bf16x8 xf = *reinterpret_cast<const bf16x8*>(&sXT[SWZ128(np * 16 + l15, j0 + kc)]);
                yac[np] = __builtin_amdgcn_mfma_f32_16x16x32_bf16(qa, xf, yac[np], 0, 0, 0);
            }
        }
    }
    #pragma unroll
    for (int kk = 0; kk < 2; ++kk) {
        const int kc = kk * 32 + l4 * 8;
        bf16x8 cf = *reinterpret_cast<const bf16x8*>(&sC[SWZ64(w16 + l15, kc)]);
        #pragma unroll
        for (int np = 0; np < 4; ++np) {
            bf16x8 pf = *reinterpret_cast<const bf16x8*>(&sP[SWZ64(np * 16 + l15, kc)]);
            iac[np] = __builtin_amdgcn_mfma_f32_16x16x32_bf16(cf, pf, iac[np], 0, 0, 0);
        }
    }
    const float dh = Dvec[h];
    #pragma unroll
    for (int jj = 0; jj < 4; ++jj) {
        const int i = w16 + l4 * 4 + jj;
        const float ei = __expf(cum[i]);
        const long m = mbase + i;
        const bf16_t* zr = xb + m * (long)IN_OUT + CONV_DIM + h * 64;
        bf16_t* orow = yz + m * (long)D_INNER + h * 64;
        #pragma unroll
        for (int np = 0; np < 4; ++np) {
            const int p = np * 16 + l15;
            const float xval = b2f(sXT[SWZ128(p, i)]);
            const float y = yac[np][jj] + ei * iac[np][jj] + dh * xval;
            const float zv = b2f(zr[p]) + zbias[h * 64 + p];
            const float s = zv / (1.f + __expf(-zv));
            orow[p] = f2b(y * s);
        }
    }
}

// ---------------------------------------------------------------------------
extern "C" void kernel_launch(void* const* d_in, const int* in_sizes, int n_in,
                              void* d_out, int out_size, void* d_ws, size_t ws_size,
                              hipStream_t stream)
{
    const float* u      = (const float*)d_in[0];
    const float* W_in   = (const float*)d_in[1];
    const float* conv_w = (const float*)d_in[2];
    const float* conv_b = (const float*)d_in[3];
    const float* Dv     = (const float*)d_in[4];
    const float* z_bias = (const float*)d_in[5];
    const float* W_out  = (const float*)d_in[6];
    float* out = (float*)d_out;

    char* w = (char*)d_ws;
    bf16_t* xbcza = (bf16_t*)w;  w += (long)M_ROWS * IN_OUT * 2;   // 128.5 MiB
    bf16_t* wob   = (bf16_t*)w;  w += (long)2048 * 2048 * 2;       //   8 MiB
    char* ureg = w;  w += 67239936;                                 // 64.1 MiB union
    bf16_t* ub  = (bf16_t*)ureg;                                    // 32 MiB (phase 1)
    bf16_t* wib = (bf16_t*)(ureg + (long)M_ROWS * D_MODEL * 2);     // 32.125 MiB (phase 1)
    bf16_t* yzb = (bf16_t*)ureg;                                    // 32 MiB (phase 2)
    float*  cumb   = (float*)(ureg + (long)M_ROWS * D_INNER * 2);   //  1 MiB @ureg+32MiB
    bf16_t* states = (bf16_t*)(cumb + (long)BATCH * NCHUNK * N_QK * CHUNK); // 16 MiB
    float*  cdec   = (float*)(states + (long)BATCH * NCHUNK * N_QK * 4096); //  8 KiB
    float* partials = (float*)(ureg + 58720256);                    // 4 MiB @ureg+56MiB
    const long base_bytes = (long)(w - (char*)d_ws);
    const long exp1_bytes = 2L * 2048 * 8192 * 2;                   // xtg + bg (64 MiB)
    const long exp2_bytes = 3L * 2048 * 8192 * 2;                   // + cg (96 MiB)
    const int expl = ((long)ws_size >= base_bytes + exp2_bytes) ? 2
                   : ((long)ws_size >= base_bytes + exp1_bytes) ? 1 : 0;
    bf16_t* xtg = (bf16_t*)w;
    bf16_t* bg  = xtg + (long)2048 * 8192;
    bf16_t* cg  = bg  + (long)2048 * 8192;

    // fused fp32->bf16 conversions (u, W_in, W_out), grid-stride
    {
        const long n0 = (long)M_ROWS * D_MODEL;
        const long n1 = (long)IN_OUT * D_MODEL;
        const long n2 = (long)D_MODEL * D_INNER;
        f2b3_kernel<<<2048, 256, 0, stream>>>(u, ub, n0, W_in, wib, n1, W_out, wob, n2);
    }

    // GEMM1 main: cols [0, 8192), 1024 wgs, bm-major
    gemm256<32, D_MODEL, true><<<(M_ROWS / 256) * 32, 512, 0, stream>>>(
        ub, wib, xbcza, IN_OUT);

    // A_log tail -> split-K partials (summed + softplus'd inside ssd_states)
    alog_partial<<<256, 256, 0, stream>>>(ub, wib + (long)8192 * D_MODEL, partials);

    dim3 sg(N_QK, NCHUNK, BATCH);
    if (expl == 2) {
        ssd_states<2><<<sg, 512, 0, stream>>>(xbcza, partials, conv_w, conv_b,
                                              states, cumb, cdec, xtg, bg, cg);
        ssd_scan<<<BATCH * N_QK * 8, 256, 0, stream>>>(states, cdec);
        ssd_out<2><<<sg, 512, 0, stream>>>(xbcza, cumb, states, Dv, z_bias,
                                           conv_w, conv_b, xtg, bg, cg, yzb);
    } else if (expl == 1) {
        ssd_states<1><<<sg, 512, 0, stream>>>(xbcza, partials, conv_w, conv_b,
                                              states, cumb, cdec, xtg, bg, nullptr);
        ssd_scan<<<BATCH * N_QK * 8, 256, 0, stream>>>(states, cdec);
        ssd_out<1><<<sg, 512, 0, stream>>>(xbcza, cumb, states, Dv, z_bias,
                                           conv_w, conv_b, xtg, bg, nullptr, yzb);
    } else {
        ssd_states<0><<<sg, 512, 0, stream>>>(xbcza, partials, conv_w, conv_b,
                                              states, cumb, cdec, nullptr, nullptr, nullptr);
        ssd_scan<<<BATCH * N_QK * 8, 256, 0, stream>>>(states, cdec);
        ssd_out<0><<<sg, 512, 0, stream>>>(xbcza, cumb, states, Dv, z_bias,
                                           conv_w, conv_b, nullptr, nullptr, nullptr, yzb);
    }

    // GEMM2: out = yz @ W_out^T  (8192 x 2048 x 2048), 256 wgs
    gemm256<8, D_INNER, false><<<(M_ROWS / 256) * 8, 512, 0, stream>>>(
        yzb, wob, out, D_MODEL);
}